// Round 1
// baseline (309.649 us; speedup 1.0000x reference)
//
#include <hip/hip_runtime.h>
#include <hip/hip_bf16.h>

// Problem constants (from reference): SEQ=2048, D=1024, H=16, P=64, FINAL=1024
#define SEQL 2048
#define DMODEL 1024
#define NH 16
#define HEADP 64
#define FINALD 1024

using bf16x8 = __attribute__((ext_vector_type(8))) short;   // 8 bf16 = 4 VGPRs (MFMA A/B frag)
using f32x4  = __attribute__((ext_vector_type(4))) float;   // MFMA C/D frag

__device__ __forceinline__ f32x4 mfma16(bf16x8 a, bf16x8 b, f32x4 c) {
  return __builtin_amdgcn_mfma_f32_16x16x32_bf16(a, b, c, 0, 0, 0);
}

__device__ __forceinline__ unsigned short f2bf(float f) {
  return __builtin_bit_cast(unsigned short, __float2bfloat16(f));
}

// ---- conversion kernels -------------------------------------------------

// f32 -> bf16, 4 elems/thread
__global__ void k_f32_to_bf16(const float* __restrict__ src,
                              unsigned short* __restrict__ dst, int n4) {
  int i = blockIdx.x * blockDim.x + threadIdx.x;
  if (i >= n4) return;
  float4 v = reinterpret_cast<const float4*>(src)[i];
  ushort4 o;
  o.x = f2bf(v.x); o.y = f2bf(v.y); o.z = f2bf(v.z); o.w = f2bf(v.w);
  reinterpret_cast<ushort4*>(dst)[i] = o;
}

// src [H][D][P] f32  ->  dst [H][P][D] bf16   (per-head transpose + convert)
__global__ void k_conv_transpose(const float* __restrict__ src,
                                 unsigned short* __restrict__ dst, int D, int P) {
  int h = blockIdx.y;
  int i = blockIdx.x * blockDim.x + threadIdx.x;
  int n = D * P;
  if (i >= n) return;
  long base = (long)h * n;
  int p = i % P, d = i / P;
  dst[base + (long)p * D + d] = f2bf(src[base + i]);
}

// ---- QKV projection: C[h] = x @ W[h],  x [S][D], Wt [P][D] (pre-transposed)
// grid (S/64, H, 3), block 256 (4 waves, each 16 rows x 64 cols)
__global__ __launch_bounds__(256) void k_qkv_proj(
    const unsigned short* __restrict__ xb,    // [S][D] bf16
    const unsigned short* __restrict__ Wt,    // [3][H][P][D] bf16
    unsigned short* __restrict__ Qb,          // [H][S][P]
    unsigned short* __restrict__ Kb,          // [H][S][P]
    unsigned short* __restrict__ Vtb) {       // [H][P][S]  (transposed V)
  int sblk = blockIdx.x, h = blockIdx.y, which = blockIdx.z;
  int lane = threadIdx.x & 63, wave = threadIdx.x >> 6;
  int r = lane & 15, g = lane >> 4;
  int row0 = sblk * 64 + wave * 16;
  const unsigned short* W = Wt + ((long)which * NH + h) * HEADP * DMODEL;
  const unsigned short* a_ptr = xb + (long)(row0 + r) * DMODEL + g * 8;
  f32x4 z4 = {0.f, 0.f, 0.f, 0.f};
  f32x4 acc[4] = {z4, z4, z4, z4};
  for (int k = 0; k < DMODEL; k += 32) {
    bf16x8 a = *reinterpret_cast<const bf16x8*>(a_ptr + k);
#pragma unroll
    for (int nb = 0; nb < 4; ++nb) {
      bf16x8 b = *reinterpret_cast<const bf16x8*>(W + (long)(nb * 16 + r) * DMODEL + k + g * 8);
      acc[nb] = mfma16(a, b, acc[nb]);
    }
  }
  // D layout: col = lane&15, row = (lane>>4)*4 + v
  if (which < 2) {
    unsigned short* out = (which == 0 ? Qb : Kb) + ((long)h * SEQL + row0) * HEADP;
#pragma unroll
    for (int nb = 0; nb < 4; ++nb)
#pragma unroll
      for (int v = 0; v < 4; ++v)
        out[(g * 4 + v) * HEADP + nb * 16 + r] = f2bf(acc[nb][v]);
  } else {
    unsigned short* out = Vtb + (long)h * HEADP * SEQL;
#pragma unroll
    for (int nb = 0; nb < 4; ++nb) {
      ushort4 pk;
      pk.x = f2bf(acc[nb][0]); pk.y = f2bf(acc[nb][1]);
      pk.z = f2bf(acc[nb][2]); pk.w = f2bf(acc[nb][3]);
      *reinterpret_cast<ushort4*>(out + (long)(nb * 16 + r) * SEQL + row0 + g * 4) = pk;
    }
  }
}

// ---- fused sigmoid attention -------------------------------------------
// attn[h,s,p] = sum_t sigmoid(Q[h,s,:].K[h,t,:]/64) * V[h,t,p]
// grid (S/64, H), block 256 (4 waves x 16 q-rows). No cross-wave sharing.
__global__ __launch_bounds__(256) void k_attn(
    const unsigned short* __restrict__ Qb,   // [H][S][P]
    const unsigned short* __restrict__ Kb,   // [H][S][P]
    const unsigned short* __restrict__ Vtb,  // [H][P][S]
    unsigned short* __restrict__ Ab) {       // [H][S][P]
  __shared__ unsigned short sc[4][16][72];   // per-wave 16x64 score slab, padded
  int sblk = blockIdx.x, h = blockIdx.y;
  int lane = threadIdx.x & 63, wave = threadIdx.x >> 6;
  int r = lane & 15, g = lane >> 4;
  int q0 = sblk * 64 + wave * 16;
  const unsigned short* Qh = Qb + ((long)h * SEQL + q0) * HEADP;
  const unsigned short* Kh = Kb + (long)h * SEQL * HEADP;
  const unsigned short* Vh = Vtb + (long)h * HEADP * SEQL;

  bf16x8 qf0 = *reinterpret_cast<const bf16x8*>(Qh + (long)r * HEADP + g * 8);
  bf16x8 qf1 = *reinterpret_cast<const bf16x8*>(Qh + (long)r * HEADP + 32 + g * 8);

  f32x4 z4 = {0.f, 0.f, 0.f, 0.f};
  f32x4 oacc[4] = {z4, z4, z4, z4};

  for (int t0 = 0; t0 < SEQL; t0 += 64) {
    // ---- S = Q @ K^T  (4 t-blocks of 16)
    f32x4 s[4] = {z4, z4, z4, z4};
#pragma unroll
    for (int tb = 0; tb < 4; ++tb) {
      const unsigned short* kp = Kh + (long)(t0 + tb * 16 + r) * HEADP + g * 8;
      bf16x8 b0 = *reinterpret_cast<const bf16x8*>(kp);
      bf16x8 b1 = *reinterpret_cast<const bf16x8*>(kp + 32);
      s[tb] = mfma16(qf0, b0, s[tb]);
      s[tb] = mfma16(qf1, b1, s[tb]);
    }
    // ---- sigmoid(S/64) -> bf16 -> LDS (per-wave slab)
#pragma unroll
    for (int tb = 0; tb < 4; ++tb)
#pragma unroll
      for (int v = 0; v < 4; ++v) {
        float xs = s[tb][v] * 0.015625f;
        float sig = 1.0f / (1.0f + __expf(-xs));
        sc[wave][g * 4 + v][tb * 16 + r] = f2bf(sig);
      }
    // ---- A-frags for PV from LDS (layout fix-up), B-frags from V^T
    bf16x8 pa0 = *reinterpret_cast<const bf16x8*>(&sc[wave][r][g * 8]);
    bf16x8 pa1 = *reinterpret_cast<const bf16x8*>(&sc[wave][r][32 + g * 8]);
#pragma unroll
    for (int nb = 0; nb < 4; ++nb) {
      const unsigned short* vp = Vh + (long)(nb * 16 + r) * SEQL + t0 + g * 8;
      bf16x8 vb0 = *reinterpret_cast<const bf16x8*>(vp);
      bf16x8 vb1 = *reinterpret_cast<const bf16x8*>(vp + 32);
      oacc[nb] = mfma16(pa0, vb0, oacc[nb]);
      oacc[nb] = mfma16(pa1, vb1, oacc[nb]);
    }
  }
  unsigned short* Oh = Ab + ((long)h * SEQL + q0) * HEADP;
#pragma unroll
  for (int nb = 0; nb < 4; ++nb)
#pragma unroll
    for (int v = 0; v < 4; ++v)
      Oh[(g * 4 + v) * HEADP + nb * 16 + r] = f2bf(oacc[nb][v]);
}

// ---- final GEMM: out = attn_flat[2048][1024] @ W_fin + b ---------------
// grid (M/64, N/64), block 256
__global__ __launch_bounds__(256) void k_final(
    const unsigned short* __restrict__ Ab,   // [2048][1024] bf16 (raw reshape of [H][S][P])
    const unsigned short* __restrict__ WfT,  // [FINAL][1024] bf16 (W_fin^T)
    const float* __restrict__ bias,
    float* __restrict__ out) {               // [2048][1024] f32
  int mb = blockIdx.x, nbk = blockIdx.y;
  int lane = threadIdx.x & 63, wave = threadIdx.x >> 6;
  int r = lane & 15, g = lane >> 4;
  int row0 = mb * 64 + wave * 16;
  int col0 = nbk * 64;
  const unsigned short* a_ptr = Ab + (long)(row0 + r) * 1024 + g * 8;
  f32x4 z4 = {0.f, 0.f, 0.f, 0.f};
  f32x4 acc[4] = {z4, z4, z4, z4};
  for (int k = 0; k < 1024; k += 32) {
    bf16x8 a = *reinterpret_cast<const bf16x8*>(a_ptr + k);
#pragma unroll
    for (int cb = 0; cb < 4; ++cb) {
      bf16x8 b = *reinterpret_cast<const bf16x8*>(WfT + (long)(col0 + cb * 16 + r) * 1024 + k + g * 8);
      acc[cb] = mfma16(a, b, acc[cb]);
    }
  }
#pragma unroll
  for (int cb = 0; cb < 4; ++cb) {
    float bv = bias[col0 + cb * 16 + r];
#pragma unroll
    for (int v = 0; v < 4; ++v)
      out[(long)(row0 + g * 4 + v) * FINALD + col0 + cb * 16 + r] = acc[cb][v] + bv;
  }
}

// ---- launch -------------------------------------------------------------
extern "C" void kernel_launch(void* const* d_in, const int* in_sizes, int n_in,
                              void* d_out, int out_size, void* d_ws, size_t ws_size,
                              hipStream_t stream) {
  const float* x  = (const float*)d_in[0];
  const float* Qw = (const float*)d_in[1];
  const float* Kw = (const float*)d_in[2];
  const float* Vw = (const float*)d_in[3];
  const float* Wf = (const float*)d_in[4];
  const float* bf = (const float*)d_in[5];
  float* out = (float*)d_out;

  unsigned short* ws  = (unsigned short*)d_ws;
  unsigned short* xb  = ws;                // [2048][1024]        2M elems
  unsigned short* Wt  = ws + 2097152;      // [3][16][64][1024]   3M
  unsigned short* WfT = ws + 5242880;      // [1024][1024]        1M
  unsigned short* Qb  = ws + 6291456;      // [16][2048][64]      2M
  unsigned short* Kb  = ws + 8388608;      // [16][2048][64]      2M
  unsigned short* Vtb = ws + 10485760;     // [16][64][2048]      2M
  unsigned short* Ab  = ws + 12582912;     // [16][2048][64]      2M
                                           // total 28 MB

  k_f32_to_bf16<<<2048, 256, 0, stream>>>(x, xb, 524288);
  k_conv_transpose<<<dim3(256, 16), 256, 0, stream>>>(Qw, Wt,            1024, 64);
  k_conv_transpose<<<dim3(256, 16), 256, 0, stream>>>(Kw, Wt + 1048576,  1024, 64);
  k_conv_transpose<<<dim3(256, 16), 256, 0, stream>>>(Vw, Wt + 2097152,  1024, 64);
  k_conv_transpose<<<dim3(4096, 1), 256, 0, stream>>>(Wf, WfT,           1024, 1024);
  k_qkv_proj<<<dim3(32, 16, 3), 256, 0, stream>>>(xb, Wt, Qb, Kb, Vtb);
  k_attn<<<dim3(32, 16), 256, 0, stream>>>(Qb, Kb, Vtb, Ab);
  k_final<<<dim3(32, 16), 256, 0, stream>>>(Ab, WfT, bf, out);
}

// Round 2
// 288.148 us; speedup vs baseline: 1.0746x; 1.0746x over previous
//
#include <hip/hip_runtime.h>
#include <hip/hip_bf16.h>

#define SEQL 2048
#define DMODEL 1024
#define NH 16
#define HEADP 64
#define FINALD 1024

using bf16x8 = __attribute__((ext_vector_type(8))) short;   // 8 bf16 (MFMA A/B frag)
using f32x4  = __attribute__((ext_vector_type(4))) float;   // MFMA C/D frag
using s16x4  = __attribute__((ext_vector_type(4))) short;   // 8B LDS write

__device__ __forceinline__ f32x4 mfma16(bf16x8 a, bf16x8 b, f32x4 c) {
  return __builtin_amdgcn_mfma_f32_16x16x32_bf16(a, b, c, 0, 0, 0);
}

__device__ __forceinline__ unsigned short f2bf(float f) {
  return __builtin_bit_cast(unsigned short, __float2bfloat16(f));
}

// ---- x f32 -> bf16 ------------------------------------------------------
__global__ void k_f32_to_bf16(const float* __restrict__ src,
                              unsigned short* __restrict__ dst, int n4) {
  int i = blockIdx.x * blockDim.x + threadIdx.x;
  if (i >= n4) return;
  float4 v = reinterpret_cast<const float4*>(src)[i];
  ushort4 o;
  o.x = f2bf(v.x); o.y = f2bf(v.y); o.z = f2bf(v.z); o.w = f2bf(v.w);
  reinterpret_cast<ushort4*>(dst)[i] = o;
}

// ---- tiled transpose+convert: src [h][R][C] f32 -> dst [h][C][R] bf16 ---
// grid (R/64, C/64, H), block 256. Coalesced on both sides.
__global__ __launch_bounds__(256) void k_transpose_cvt(
    const float* __restrict__ src, unsigned short* __restrict__ dst,
    int R, int C) {
  __shared__ float tile[64][65];
  int tr = blockIdx.x * 64, tc = blockIdx.y * 64, h = blockIdx.z;
  const float* s = src + (long)h * R * C;
  unsigned short* d = dst + (long)h * R * C;
  int t = threadIdx.x;
  int r0 = t >> 4, c4 = (t & 15) * 4;
#pragma unroll
  for (int i = 0; i < 4; ++i) {
    int r = i * 16 + r0;
    float4 v = *reinterpret_cast<const float4*>(s + (long)(tr + r) * C + tc + c4);
    tile[r][c4 + 0] = v.x; tile[r][c4 + 1] = v.y;
    tile[r][c4 + 2] = v.z; tile[r][c4 + 3] = v.w;
  }
  __syncthreads();
  int r4 = (t & 15) * 4, cc0 = t >> 4;
#pragma unroll
  for (int i = 0; i < 4; ++i) {
    int c = i * 16 + cc0;
    ushort4 o;
    o.x = f2bf(tile[r4 + 0][c]); o.y = f2bf(tile[r4 + 1][c]);
    o.z = f2bf(tile[r4 + 2][c]); o.w = f2bf(tile[r4 + 3][c]);
    *reinterpret_cast<ushort4*>(d + (long)(tc + c) * R + tr + r4) = o;
  }
}

// ---- QKV projection (as round 1) ---------------------------------------
__global__ __launch_bounds__(256) void k_qkv_proj(
    const unsigned short* __restrict__ xb,    // [S][D] bf16
    const unsigned short* __restrict__ Wt,    // [3][H][P][D] bf16
    unsigned short* __restrict__ Qb,          // [H][S][P]
    unsigned short* __restrict__ Kb,          // [H][S][P]
    unsigned short* __restrict__ Vtb) {       // [H][P][S]
  int sblk = blockIdx.x, h = blockIdx.y, which = blockIdx.z;
  int lane = threadIdx.x & 63, wave = threadIdx.x >> 6;
  int r = lane & 15, g = lane >> 4;
  int row0 = sblk * 64 + wave * 16;
  const unsigned short* W = Wt + ((long)which * NH + h) * HEADP * DMODEL;
  const unsigned short* a_ptr = xb + (long)(row0 + r) * DMODEL + g * 8;
  f32x4 z4 = {0.f, 0.f, 0.f, 0.f};
  f32x4 acc[4] = {z4, z4, z4, z4};
  for (int k = 0; k < DMODEL; k += 32) {
    bf16x8 a = *reinterpret_cast<const bf16x8*>(a_ptr + k);
#pragma unroll
    for (int nb = 0; nb < 4; ++nb) {
      bf16x8 b = *reinterpret_cast<const bf16x8*>(W + (long)(nb * 16 + r) * DMODEL + k + g * 8);
      acc[nb] = mfma16(a, b, acc[nb]);
    }
  }
  if (which < 2) {
    unsigned short* out = (which == 0 ? Qb : Kb) + ((long)h * SEQL + row0) * HEADP;
#pragma unroll
    for (int nb = 0; nb < 4; ++nb)
#pragma unroll
      for (int v = 0; v < 4; ++v)
        out[(g * 4 + v) * HEADP + nb * 16 + r] = f2bf(acc[nb][v]);
  } else {
    unsigned short* out = Vtb + (long)h * HEADP * SEQL;
#pragma unroll
    for (int nb = 0; nb < 4; ++nb) {
      ushort4 pk;
      pk.x = f2bf(acc[nb][0]); pk.y = f2bf(acc[nb][1]);
      pk.z = f2bf(acc[nb][2]); pk.w = f2bf(acc[nb][3]);
      *reinterpret_cast<ushort4*>(out + (long)(nb * 16 + r) * SEQL + row0 + g * 4) = pk;
    }
  }
}

// ---- fused sigmoid attention, t-split 2-way, XCD-localized heads -------
// grid 1024 (1D), block 256 (4 waves x 16 q-rows).
__global__ __launch_bounds__(256) void k_attn(
    const unsigned short* __restrict__ Qb,   // [H][S][P]
    const unsigned short* __restrict__ Kb,   // [H][S][P]
    const unsigned short* __restrict__ Vtb,  // [H][P][S]
    float* __restrict__ P0,                  // partial t-chunk 0 (=d_out)
    float* __restrict__ P1) {                // partial t-chunk 1
  __shared__ unsigned short sc[4][16][64];   // per-wave slab, XOR-swizzled
  int b = blockIdx.x;
  int xcd = b & 7, j = b >> 3;
  int h = xcd + 8 * (j & 1);      // each XCD owns heads {xcd, xcd+8}
  int sblk = (j >> 1) & 31;
  int tc = j >> 6;                // 0..1
  int lane = threadIdx.x & 63, wave = threadIdx.x >> 6;
  int r = lane & 15, g = lane >> 4;
  int q0 = sblk * 64 + wave * 16;
  const unsigned short* Qh = Qb + ((long)h * SEQL + q0) * HEADP;
  const unsigned short* Kh = Kb + (long)h * SEQL * HEADP;
  const unsigned short* Vh = Vtb + (long)h * HEADP * SEQL;

  bf16x8 qf0 = *reinterpret_cast<const bf16x8*>(Qh + (long)r * HEADP + g * 8);
  bf16x8 qf1 = *reinterpret_cast<const bf16x8*>(Qh + (long)r * HEADP + 32 + g * 8);

  f32x4 z4 = {0.f, 0.f, 0.f, 0.f};
  f32x4 oacc[4] = {z4, z4, z4, z4};
  char* slab = (char*)&sc[wave][0][0];
  int swz = (r & 7) << 4;
  const float CLN = -0.02254211001389005f;   // -log2(e)/64

  int tbeg = tc * (SEQL / 2), tend = tbeg + SEQL / 2;
  for (int t0 = tbeg; t0 < tend; t0 += 64) {
    // V-frag loads first: latency hides under QK^T + sigmoid
    bf16x8 vb0[4], vb1[4];
#pragma unroll
    for (int nb = 0; nb < 4; ++nb) {
      const unsigned short* vp = Vh + (long)(nb * 16 + r) * SEQL + t0 + g * 8;
      vb0[nb] = *reinterpret_cast<const bf16x8*>(vp);
      vb1[nb] = *reinterpret_cast<const bf16x8*>(vp + 32);
    }
    // S^T = K @ Q^T : lane holds S[t=tb*16+g*4+v][q=r]
    f32x4 s[4] = {z4, z4, z4, z4};
#pragma unroll
    for (int tb = 0; tb < 4; ++tb) {
      const unsigned short* kp = Kh + (long)(t0 + tb * 16 + r) * HEADP + g * 8;
      bf16x8 k0 = *reinterpret_cast<const bf16x8*>(kp);
      bf16x8 k1 = *reinterpret_cast<const bf16x8*>(kp + 32);
      s[tb] = mfma16(k0, qf0, s[tb]);
      s[tb] = mfma16(k1, qf1, s[tb]);
    }
    // sigmoid(S/64) -> bf16, 8B vectorized LDS write at [q=r][t], swizzled
#pragma unroll
    for (int tb = 0; tb < 4; ++tb) {
      s16x4 pk;
#pragma unroll
      for (int v = 0; v < 4; ++v) {
        float e = __builtin_amdgcn_exp2f(s[tb][v] * CLN);
        pk[v] = (short)f2bf(__builtin_amdgcn_rcpf(1.0f + e));
      }
      *reinterpret_cast<s16x4*>(slab + r * 128 + ((tb * 32 + g * 8) ^ swz)) = pk;
    }
    // A-frags for PV: row q=r, t-chunks of 32 (perfect 2-way banked)
    bf16x8 pa0 = *reinterpret_cast<const bf16x8*>(slab + r * 128 + ((g * 16) ^ swz));
    bf16x8 pa1 = *reinterpret_cast<const bf16x8*>(slab + r * 128 + ((64 + g * 16) ^ swz));
#pragma unroll
    for (int nb = 0; nb < 4; ++nb) {
      oacc[nb] = mfma16(pa0, vb0[nb], oacc[nb]);
      oacc[nb] = mfma16(pa1, vb1[nb], oacc[nb]);
    }
  }
  float* Po = (tc ? P1 : P0) + ((long)h * SEQL + q0) * HEADP;
#pragma unroll
  for (int nb = 0; nb < 4; ++nb)
#pragma unroll
    for (int v = 0; v < 4; ++v)
      Po[(g * 4 + v) * HEADP + nb * 16 + r] = oacc[nb][v];
}

// ---- reduce partials -> bf16 attn --------------------------------------
__global__ void k_reduce(const float* __restrict__ P0, const float* __restrict__ P1,
                         unsigned short* __restrict__ Ab, int n4) {
  int i = blockIdx.x * blockDim.x + threadIdx.x;
  if (i >= n4) return;
  float4 a = reinterpret_cast<const float4*>(P0)[i];
  float4 b = reinterpret_cast<const float4*>(P1)[i];
  ushort4 o;
  o.x = f2bf(a.x + b.x); o.y = f2bf(a.y + b.y);
  o.z = f2bf(a.z + b.z); o.w = f2bf(a.w + b.w);
  reinterpret_cast<ushort4*>(Ab)[i] = o;
}

// ---- final GEMM (as round 1) -------------------------------------------
__global__ __launch_bounds__(256) void k_final(
    const unsigned short* __restrict__ Ab,   // [2048][1024] bf16
    const unsigned short* __restrict__ WfT,  // [FINAL][1024] bf16
    const float* __restrict__ bias,
    float* __restrict__ out) {
  int mb = blockIdx.x, nbk = blockIdx.y;
  int lane = threadIdx.x & 63, wave = threadIdx.x >> 6;
  int r = lane & 15, g = lane >> 4;
  int row0 = mb * 64 + wave * 16;
  int col0 = nbk * 64;
  const unsigned short* a_ptr = Ab + (long)(row0 + r) * 1024 + g * 8;
  f32x4 z4 = {0.f, 0.f, 0.f, 0.f};
  f32x4 acc[4] = {z4, z4, z4, z4};
  for (int k = 0; k < 1024; k += 32) {
    bf16x8 a = *reinterpret_cast<const bf16x8*>(a_ptr + k);
#pragma unroll
    for (int cb = 0; cb < 4; ++cb) {
      bf16x8 b = *reinterpret_cast<const bf16x8*>(WfT + (long)(col0 + cb * 16 + r) * 1024 + k + g * 8);
      acc[cb] = mfma16(a, b, acc[cb]);
    }
  }
#pragma unroll
  for (int cb = 0; cb < 4; ++cb) {
    float bv = bias[col0 + cb * 16 + r];
#pragma unroll
    for (int v = 0; v < 4; ++v)
      out[(long)(row0 + g * 4 + v) * FINALD + col0 + cb * 16 + r] = acc[cb][v] + bv;
  }
}

// ---- launch -------------------------------------------------------------
extern "C" void kernel_launch(void* const* d_in, const int* in_sizes, int n_in,
                              void* d_out, int out_size, void* d_ws, size_t ws_size,
                              hipStream_t stream) {
  const float* x  = (const float*)d_in[0];
  const float* Qw = (const float*)d_in[1];
  const float* Kw = (const float*)d_in[2];
  const float* Vw = (const float*)d_in[3];
  const float* Wf = (const float*)d_in[4];
  const float* bf = (const float*)d_in[5];
  float* out = (float*)d_out;

  unsigned short* ws  = (unsigned short*)d_ws;
  unsigned short* xb  = ws;                // [2048][1024]       bytes [0,4M)
  unsigned short* Wt  = ws + 2097152;      // [3][16][64][1024]  bytes [4M,10M)
  unsigned short* WfT = ws + 5242880;      // [1024][1024]       bytes [10M,12M)
  unsigned short* Qb  = ws + 6291456;      // [16][2048][64]     bytes [12M,16M)
  unsigned short* Kb  = ws + 8388608;      //                    bytes [16M,20M)
  unsigned short* Vtb = ws + 10485760;     // [16][64][2048]     bytes [20M,24M)
  unsigned short* Ab  = ws + 12582912;     // [16][2048][64]     bytes [24M,28M)
  float* P0 = (float*)d_out;               // partial 0: d_out as scratch (8MB)
  float* P1 = (float*)d_ws;                // partial 1: overlays dead xb/Wt (8MB)

  k_f32_to_bf16<<<2048, 256, 0, stream>>>(x, xb, 524288);
  k_transpose_cvt<<<dim3(16, 1, 16), 256, 0, stream>>>(Qw, Wt,           DMODEL, HEADP);
  k_transpose_cvt<<<dim3(16, 1, 16), 256, 0, stream>>>(Kw, Wt + 1048576, DMODEL, HEADP);
  k_transpose_cvt<<<dim3(16, 1, 16), 256, 0, stream>>>(Vw, Wt + 2097152, DMODEL, HEADP);
  k_transpose_cvt<<<dim3(16, 16, 1), 256, 0, stream>>>(Wf, WfT,          DMODEL, FINALD);
  k_qkv_proj<<<dim3(32, 16, 3), 256, 0, stream>>>(xb, Wt, Qb, Kb, Vtb);
  k_attn<<<1024, 256, 0, stream>>>(Qb, Kb, Vtb, P0, P1);
  k_reduce<<<2048, 256, 0, stream>>>(P0, P1, Ab, 524288);
  k_final<<<dim3(32, 16), 256, 0, stream>>>(Ab, WfT, bf, out);
}

// Round 3
// 202.694 us; speedup vs baseline: 1.5277x; 1.4216x over previous
//
#include <hip/hip_runtime.h>
#include <hip/hip_bf16.h>

#define SEQL 2048
#define DMODEL 1024
#define NH 16
#define HEADP 64
#define FINALD 1024

using bf16x8 = __attribute__((ext_vector_type(8))) short;   // 8 bf16 (MFMA A/B frag)
using f32x4  = __attribute__((ext_vector_type(4))) float;   // MFMA C/D frag
using s16x4  = __attribute__((ext_vector_type(4))) short;   // 8B LDS write

__device__ __forceinline__ f32x4 mfma16(bf16x8 a, bf16x8 b, f32x4 c) {
  return __builtin_amdgcn_mfma_f32_16x16x32_bf16(a, b, c, 0, 0, 0);
}

__device__ __forceinline__ unsigned short f2bf(float f) {
  return __builtin_bit_cast(unsigned short, __float2bfloat16(f));
}

// async global->LDS, 16B per lane; LDS dest = wave-uniform base + lane*16
__device__ __forceinline__ void gload16(const void* g, void* l) {
  __builtin_amdgcn_global_load_lds(
      (const __attribute__((address_space(1))) void*)g,
      (__attribute__((address_space(3))) void*)l, 16, 0, 0);
}

// ---- x f32 -> bf16 ------------------------------------------------------
__global__ void k_f32_to_bf16(const float* __restrict__ src,
                              unsigned short* __restrict__ dst, int n4) {
  int i = blockIdx.x * blockDim.x + threadIdx.x;
  if (i >= n4) return;
  float4 v = reinterpret_cast<const float4*>(src)[i];
  ushort4 o;
  o.x = f2bf(v.x); o.y = f2bf(v.y); o.z = f2bf(v.z); o.w = f2bf(v.w);
  reinterpret_cast<ushort4*>(dst)[i] = o;
}

// ---- tiled transpose+convert: src [h][R][C] f32 -> dst [h][C][R] bf16 ---
__global__ __launch_bounds__(256) void k_transpose_cvt(
    const float* __restrict__ src, unsigned short* __restrict__ dst,
    int R, int C) {
  __shared__ float tile[64][65];
  int tr = blockIdx.x * 64, tc = blockIdx.y * 64, h = blockIdx.z;
  const float* s = src + (long)h * R * C;
  unsigned short* d = dst + (long)h * R * C;
  int t = threadIdx.x;
  int r0 = t >> 4, c4 = (t & 15) * 4;
#pragma unroll
  for (int i = 0; i < 4; ++i) {
    int r = i * 16 + r0;
    float4 v = *reinterpret_cast<const float4*>(s + (long)(tr + r) * C + tc + c4);
    tile[r][c4 + 0] = v.x; tile[r][c4 + 1] = v.y;
    tile[r][c4 + 2] = v.z; tile[r][c4 + 3] = v.w;
  }
  __syncthreads();
  int r4 = (t & 15) * 4, cc0 = t >> 4;
#pragma unroll
  for (int i = 0; i < 4; ++i) {
    int c = i * 16 + cc0;
    ushort4 o;
    o.x = f2bf(tile[r4 + 0][c]); o.y = f2bf(tile[r4 + 1][c]);
    o.z = f2bf(tile[r4 + 2][c]); o.w = f2bf(tile[r4 + 3][c]);
    *reinterpret_cast<ushort4*>(d + (long)(tc + c) * R + tr + r4) = o;
  }
}

// ---- QKV projection (unchanged) ----------------------------------------
__global__ __launch_bounds__(256) void k_qkv_proj(
    const unsigned short* __restrict__ xb,    // [S][D] bf16
    const unsigned short* __restrict__ Wt,    // [3][H][P][D] bf16
    unsigned short* __restrict__ Qb,          // [H][S][P]
    unsigned short* __restrict__ Kb,          // [H][S][P]
    unsigned short* __restrict__ Vtb) {       // [H][P][S]
  int sblk = blockIdx.x, h = blockIdx.y, which = blockIdx.z;
  int lane = threadIdx.x & 63, wave = threadIdx.x >> 6;
  int r = lane & 15, g = lane >> 4;
  int row0 = sblk * 64 + wave * 16;
  const unsigned short* W = Wt + ((long)which * NH + h) * HEADP * DMODEL;
  const unsigned short* a_ptr = xb + (long)(row0 + r) * DMODEL + g * 8;
  f32x4 z4 = {0.f, 0.f, 0.f, 0.f};
  f32x4 acc[4] = {z4, z4, z4, z4};
  for (int k = 0; k < DMODEL; k += 32) {
    bf16x8 a = *reinterpret_cast<const bf16x8*>(a_ptr + k);
#pragma unroll
    for (int nb = 0; nb < 4; ++nb) {
      bf16x8 b = *reinterpret_cast<const bf16x8*>(W + (long)(nb * 16 + r) * DMODEL + k + g * 8);
      acc[nb] = mfma16(a, b, acc[nb]);
    }
  }
  if (which < 2) {
    unsigned short* out = (which == 0 ? Qb : Kb) + ((long)h * SEQL + row0) * HEADP;
#pragma unroll
    for (int nb = 0; nb < 4; ++nb)
#pragma unroll
      for (int v = 0; v < 4; ++v)
        out[(g * 4 + v) * HEADP + nb * 16 + r] = f2bf(acc[nb][v]);
  } else {
    unsigned short* out = Vtb + (long)h * HEADP * SEQL;
#pragma unroll
    for (int nb = 0; nb < 4; ++nb) {
      ushort4 pk;
      pk.x = f2bf(acc[nb][0]); pk.y = f2bf(acc[nb][1]);
      pk.z = f2bf(acc[nb][2]); pk.w = f2bf(acc[nb][3]);
      *reinterpret_cast<ushort4*>(out + (long)(nb * 16 + r) * SEQL + row0 + g * 4) = pk;
    }
  }
}

// ---- fused sigmoid attention: LDS-staged K/V, double-buffered ----------
// grid 1024, block 256 (4 waves x 16 q-rows). t-split 2-way.
// LDS: 2 x (K tile 8KB + V tile 8KB) + 4 x 2KB score slab = 40KB.
// K/V tiles stored [64 rows][128B] with chunk-XOR swizzle (chunk ^= row&7),
// applied on the GLOBAL source so the LDS dest stays linear (rule #21).
__global__ __launch_bounds__(256) void k_attn(
    const unsigned short* __restrict__ Qb,   // [H][S][P]
    const unsigned short* __restrict__ Kb,   // [H][S][P]
    const unsigned short* __restrict__ Vtb,  // [H][P][S]
    float* __restrict__ P0,                  // partial t-chunk 0 (=d_out)
    float* __restrict__ P1) {                // partial t-chunk 1
  __shared__ char lds[40960];
  int b = blockIdx.x;
  int xcd = b & 7, j = b >> 3;
  int h = xcd + 8 * (j & 1);      // each XCD owns heads {xcd, xcd+8}
  int sblk = (j >> 1) & 31;
  int tc = j >> 6;                // 0..1
  int lane = threadIdx.x & 63, wave = threadIdx.x >> 6;
  int r = lane & 15, g = lane >> 4;
  int q0 = sblk * 64 + wave * 16;
  const unsigned short* Qh = Qb + ((long)h * SEQL + q0) * HEADP;
  const unsigned short* Kh = Kb + (long)h * SEQL * HEADP;
  const unsigned short* Vh = Vtb + (long)h * HEADP * SEQL;

  bf16x8 qf0 = *reinterpret_cast<const bf16x8*>(Qh + (long)r * HEADP + g * 8);
  bf16x8 qf1 = *reinterpret_cast<const bf16x8*>(Qh + (long)r * HEADP + 32 + g * 8);

  f32x4 z4 = {0.f, 0.f, 0.f, 0.f};
  f32x4 oacc[4] = {z4, z4, z4, z4};
  char* slab = lds + 32768 + wave * 2048;
  int swz = (r & 7) << 4;
  const float CLN = -0.02254211001389005f;   // -log2(e)/64

  int sub = lane >> 3, chunk = lane & 7;
  // stage K rows / V^T rows [wave*16 .. +15] of tile t0 into buffer `buf`
  auto stage = [&](int buf, int t0) {
    char* kb = lds + buf * 16384 + wave * 2048;
    char* vb = kb + 8192;
#pragma unroll
    for (int jj = 0; jj < 2; ++jj) {
      int row = wave * 16 + jj * 8 + sub;
      int sw = (chunk ^ (row & 7)) * 8;
      gload16(Kh + (long)(t0 + row) * HEADP + sw, kb + jj * 1024);
      gload16(Vh + (long)row * SEQL + t0 + sw, vb + jj * 1024);
    }
  };

  int tbeg = tc * (SEQL / 2), tend = tbeg + SEQL / 2;
  int cur = 0;
  stage(0, tbeg);
  __syncthreads();
  for (int t0 = tbeg; t0 < tend; t0 += 64) {
    if (t0 + 64 < tend) stage(cur ^ 1, t0 + 64);   // prefetch next tile

    const char* kb = lds + cur * 16384;
    const char* vb = kb + 8192;
    // S^T = K @ Q^T : lane holds S[t=tb*16+g*4+v][q=r]
    f32x4 s[4] = {z4, z4, z4, z4};
#pragma unroll
    for (int tb = 0; tb < 4; ++tb) {
      const char* krow = kb + (tb * 16 + r) * 128;
      bf16x8 k0 = *reinterpret_cast<const bf16x8*>(krow + ((g ^ (r & 7)) * 16));
      bf16x8 k1 = *reinterpret_cast<const bf16x8*>(krow + (((4 + g) ^ (r & 7)) * 16));
      s[tb] = mfma16(k0, qf0, s[tb]);
      s[tb] = mfma16(k1, qf1, s[tb]);
    }
    // sigmoid(S/64) -> bf16 -> per-wave slab (8B writes, swizzled)
#pragma unroll
    for (int tb = 0; tb < 4; ++tb) {
      s16x4 pk;
#pragma unroll
      for (int v = 0; v < 4; ++v) {
        float e = __builtin_amdgcn_exp2f(s[tb][v] * CLN);
        pk[v] = (short)f2bf(__builtin_amdgcn_rcpf(1.0f + e));
      }
      *reinterpret_cast<s16x4*>(slab + r * 128 + ((tb * 32 + g * 8) ^ swz)) = pk;
    }
    // PV: A-frags from slab, B-frags from V tile in LDS
    bf16x8 pa0 = *reinterpret_cast<const bf16x8*>(slab + r * 128 + ((g * 16) ^ swz));
    bf16x8 pa1 = *reinterpret_cast<const bf16x8*>(slab + r * 128 + ((64 + g * 16) ^ swz));
#pragma unroll
    for (int nb = 0; nb < 4; ++nb) {
      const char* vrow = vb + (nb * 16 + r) * 128;
      bf16x8 v0 = *reinterpret_cast<const bf16x8*>(vrow + ((g ^ (r & 7)) * 16));
      bf16x8 v1 = *reinterpret_cast<const bf16x8*>(vrow + (((4 + g) ^ (r & 7)) * 16));
      oacc[nb] = mfma16(pa0, v0, oacc[nb]);
      oacc[nb] = mfma16(pa1, v1, oacc[nb]);
    }
    __syncthreads();   // drains prefetch (vmcnt) + all LDS reads of cur
    cur ^= 1;
  }
  float* Po = (tc ? P1 : P0) + ((long)h * SEQL + q0) * HEADP;
#pragma unroll
  for (int nb = 0; nb < 4; ++nb)
#pragma unroll
    for (int v = 0; v < 4; ++v)
      Po[(g * 4 + v) * HEADP + nb * 16 + r] = oacc[nb][v];
}

// ---- reduce partials -> bf16 attn --------------------------------------
__global__ void k_reduce(const float* __restrict__ P0, const float* __restrict__ P1,
                         unsigned short* __restrict__ Ab, int n4) {
  int i = blockIdx.x * blockDim.x + threadIdx.x;
  if (i >= n4) return;
  float4 a = reinterpret_cast<const float4*>(P0)[i];
  float4 b = reinterpret_cast<const float4*>(P1)[i];
  ushort4 o;
  o.x = f2bf(a.x + b.x); o.y = f2bf(a.y + b.y);
  o.z = f2bf(a.z + b.z); o.w = f2bf(a.w + b.w);
  reinterpret_cast<ushort4*>(Ab)[i] = o;
}

// ---- final GEMM (unchanged) --------------------------------------------
__global__ __launch_bounds__(256) void k_final(
    const unsigned short* __restrict__ Ab,   // [2048][1024] bf16
    const unsigned short* __restrict__ WfT,  // [FINAL][1024] bf16
    const float* __restrict__ bias,
    float* __restrict__ out) {
  int mb = blockIdx.x, nbk = blockIdx.y;
  int lane = threadIdx.x & 63, wave = threadIdx.x >> 6;
  int r = lane & 15, g = lane >> 4;
  int row0 = mb * 64 + wave * 16;
  int col0 = nbk * 64;
  const unsigned short* a_ptr = Ab + (long)(row0 + r) * 1024 + g * 8;
  f32x4 z4 = {0.f, 0.f, 0.f, 0.f};
  f32x4 acc[4] = {z4, z4, z4, z4};
  for (int k = 0; k < 1024; k += 32) {
    bf16x8 a = *reinterpret_cast<const bf16x8*>(a_ptr + k);
#pragma unroll
    for (int cb = 0; cb < 4; ++cb) {
      bf16x8 b = *reinterpret_cast<const bf16x8*>(WfT + (long)(col0 + cb * 16 + r) * 1024 + k + g * 8);
      acc[cb] = mfma16(a, b, acc[cb]);
    }
  }
#pragma unroll
  for (int cb = 0; cb < 4; ++cb) {
    float bv = bias[col0 + cb * 16 + r];
#pragma unroll
    for (int v = 0; v < 4; ++v)
      out[(long)(row0 + g * 4 + v) * FINALD + col0 + cb * 16 + r] = acc[cb][v] + bv;
  }
}

// ---- launch -------------------------------------------------------------
extern "C" void kernel_launch(void* const* d_in, const int* in_sizes, int n_in,
                              void* d_out, int out_size, void* d_ws, size_t ws_size,
                              hipStream_t stream) {
  const float* x  = (const float*)d_in[0];
  const float* Qw = (const float*)d_in[1];
  const float* Kw = (const float*)d_in[2];
  const float* Vw = (const float*)d_in[3];
  const float* Wf = (const float*)d_in[4];
  const float* bf = (const float*)d_in[5];
  float* out = (float*)d_out;

  unsigned short* ws  = (unsigned short*)d_ws;
  unsigned short* xb  = ws;                // [2048][1024]       bytes [0,4M)
  unsigned short* Wt  = ws + 2097152;      // [3][16][64][1024]  bytes [4M,10M)
  unsigned short* WfT = ws + 5242880;      // [1024][1024]       bytes [10M,12M)
  unsigned short* Qb  = ws + 6291456;      // [16][2048][64]     bytes [12M,16M)
  unsigned short* Kb  = ws + 8388608;      //                    bytes [16M,20M)
  unsigned short* Vtb = ws + 10485760;     // [16][64][2048]     bytes [20M,24M)
  unsigned short* Ab  = ws + 12582912;     // [16][2048][64]     bytes [24M,28M)
  float* P0 = (float*)d_out;               // partial 0: d_out as scratch (8MB)
  float* P1 = (float*)d_ws;                // partial 1: overlays dead xb/Wt (8MB)

  k_f32_to_bf16<<<2048, 256, 0, stream>>>(x, xb, 524288);
  k_transpose_cvt<<<dim3(16, 1, 16), 256, 0, stream>>>(Qw, Wt,           DMODEL, HEADP);
  k_transpose_cvt<<<dim3(16, 1, 16), 256, 0, stream>>>(Kw, Wt + 1048576, DMODEL, HEADP);
  k_transpose_cvt<<<dim3(16, 1, 16), 256, 0, stream>>>(Vw, Wt + 2097152, DMODEL, HEADP);
  k_transpose_cvt<<<dim3(16, 16, 1), 256, 0, stream>>>(Wf, WfT,          DMODEL, FINALD);
  k_qkv_proj<<<dim3(32, 16, 3), 256, 0, stream>>>(xb, Wt, Qb, Kb, Vtb);
  k_attn<<<1024, 256, 0, stream>>>(Qb, Kb, Vtb, P0, P1);
  k_reduce<<<2048, 256, 0, stream>>>(P0, P1, Ab, 524288);
  k_final<<<dim3(32, 16), 256, 0, stream>>>(Ab, WfT, bf, out);
}

// Round 4
// 100.565 us; speedup vs baseline: 3.0791x; 2.0156x over previous
//
#include <hip/hip_runtime.h>
#include <hip/hip_bf16.h>

#define SEQL 2048
#define DMODEL 1024
#define NH 16
#define HEADP 64
#define FINALD 1024

using bf16x8 = __attribute__((ext_vector_type(8))) short;   // 8 bf16 (MFMA A/B frag)
using f32x4  = __attribute__((ext_vector_type(4))) float;   // MFMA C/D frag
using s16x4  = __attribute__((ext_vector_type(4))) short;   // 8B LDS write

__device__ __forceinline__ f32x4 mfma16(bf16x8 a, bf16x8 b, f32x4 c) {
  return __builtin_amdgcn_mfma_f32_16x16x32_bf16(a, b, c, 0, 0, 0);
}

__device__ __forceinline__ unsigned short f2bf(float f) {
  return __builtin_bit_cast(unsigned short, __float2bfloat16(f));
}

// async global->LDS, 16B/lane; LDS dest = wave-uniform base + lane*16
__device__ __forceinline__ void gload16(const void* g, void* l) {
  __builtin_amdgcn_global_load_lds(
      (const __attribute__((address_space(1))) void*)g,
      (__attribute__((address_space(3))) void*)l, 16, 0, 0);
}

// ---- x f32 -> bf16 ------------------------------------------------------
__global__ void k_f32_to_bf16(const float* __restrict__ src,
                              unsigned short* __restrict__ dst, int n4) {
  int i = blockIdx.x * blockDim.x + threadIdx.x;
  if (i >= n4) return;
  float4 v = reinterpret_cast<const float4*>(src)[i];
  ushort4 o;
  o.x = f2bf(v.x); o.y = f2bf(v.y); o.z = f2bf(v.z); o.w = f2bf(v.w);
  reinterpret_cast<ushort4*>(dst)[i] = o;
}

// ---- tiled transpose+convert: src [h][R][C] f32 -> dst [h][C][R] bf16 ---
__global__ __launch_bounds__(256) void k_transpose_cvt(
    const float* __restrict__ src, unsigned short* __restrict__ dst,
    int R, int C) {
  __shared__ float tile[64][65];
  int tr = blockIdx.x * 64, tc = blockIdx.y * 64, h = blockIdx.z;
  const float* s = src + (long)h * R * C;
  unsigned short* d = dst + (long)h * R * C;
  int t = threadIdx.x;
  int r0 = t >> 4, c4 = (t & 15) * 4;
#pragma unroll
  for (int i = 0; i < 4; ++i) {
    int r = i * 16 + r0;
    float4 v = *reinterpret_cast<const float4*>(s + (long)(tr + r) * C + tc + c4);
    tile[r][c4 + 0] = v.x; tile[r][c4 + 1] = v.y;
    tile[r][c4 + 2] = v.z; tile[r][c4 + 3] = v.w;
  }
  __syncthreads();
  int r4 = (t & 15) * 4, cc0 = t >> 4;
#pragma unroll
  for (int i = 0; i < 4; ++i) {
    int c = i * 16 + cc0;
    ushort4 o;
    o.x = f2bf(tile[r4 + 0][c]); o.y = f2bf(tile[r4 + 1][c]);
    o.z = f2bf(tile[r4 + 2][c]); o.w = f2bf(tile[r4 + 3][c]);
    *reinterpret_cast<ushort4*>(d + (long)(tc + c) * R + tr + r4) = o;
  }
}

// ---- unified LDS-staged GEMM (m97 structure) ---------------------------
// C[M,N] = A[M,K] @ Bt[N,K]^T.  128x128 tile, BK=32, 4 waves x (4x4 frags),
// double-buffered LDS, global_load_lds staging, 2-phase loop.
// EPI=0: QKV epilogue (N=3072: which=n0/1024; Q/K scatter, V transposed)
// EPI=1: f32 + bias epilogue (final GEMM)
template <int EPI>
__global__ __launch_bounds__(256) void k_gemm(
    const unsigned short* __restrict__ A,    // [M][K] bf16
    const unsigned short* __restrict__ Bt,   // [N][K] bf16 (B^T)
    int K,
    unsigned short* __restrict__ Qb,         // [H][S][P]
    unsigned short* __restrict__ Kb,         // [H][S][P]
    unsigned short* __restrict__ Vtb,        // [H][P][S]
    const float* __restrict__ bias,
    float* __restrict__ outf) {              // [S][FINAL]
  __shared__ char lds[32768];                // 2 x (A 8KB + B 8KB)
  int m0 = blockIdx.x * 128, n0 = blockIdx.y * 128;
  int t = threadIdx.x;
  int l = t & 63, w = t >> 6;
  int r = l & 15, g = l >> 4;
  int wr = w >> 1, wc = w & 1;               // wave -> 64x64 quadrant

  const unsigned short* Arow = A + (long)m0 * K;
  const unsigned short* Brow = Bt + (long)n0 * K;
  int rA = w * 16 + (l >> 2), c8 = (l & 3) * 8;

  auto stage = [&](int buf, int k0) {
    char* dstA = lds + buf * 16384 + w * 1024;   // wave-uniform dest
    char* dstB = dstA + 8192;
#pragma unroll
    for (int j = 0; j < 2; ++j) {
      gload16(Arow + (long)(j * 64 + rA) * K + k0 + c8, dstA + j * 4096);
      gload16(Brow + (long)(j * 64 + rA) * K + k0 + c8, dstB + j * 4096);
    }
  };

  f32x4 acc[4][4] = {};
  int cur = 0, NK = K / 32;
  stage(0, 0);
  __syncthreads();
  for (int kt = 0; kt < NK; ++kt) {
    if (kt + 1 < NK) stage(cur ^ 1, (kt + 1) * 32);   // prefetch next K-tile
    const char* As = lds + cur * 16384;
    const char* Bs = As + 8192;
    bf16x8 af[4], bb[4];
#pragma unroll
    for (int i = 0; i < 4; ++i)
      af[i] = *reinterpret_cast<const bf16x8*>(As + (wr * 64 + i * 16 + r) * 64 + g * 16);
#pragma unroll
    for (int i = 0; i < 4; ++i)
      bb[i] = *reinterpret_cast<const bf16x8*>(Bs + (wc * 64 + i * 16 + r) * 64 + g * 16);
#pragma unroll
    for (int mi = 0; mi < 4; ++mi)
#pragma unroll
      for (int ni = 0; ni < 4; ++ni)
        acc[mi][ni] = mfma16(af[mi], bb[ni], acc[mi][ni]);
    __syncthreads();   // waves done with cur; prefetch (vmcnt) drained
    cur ^= 1;
  }

  if constexpr (EPI == 0) {
    int which = n0 >> 10;
    int hb = ((n0 & 1023) >> 6) + wc;       // head for this wave's columns
    if (which < 2) {
      unsigned short* dst = (which == 0 ? Qb : Kb) + (long)hb * SEQL * HEADP;
#pragma unroll
      for (int mi = 0; mi < 4; ++mi) {
        int s0 = m0 + wr * 64 + mi * 16 + g * 4;
#pragma unroll
        for (int ni = 0; ni < 4; ++ni) {
          int p = ni * 16 + r;
#pragma unroll
          for (int v = 0; v < 4; ++v)
            dst[(long)(s0 + v) * HEADP + p] = f2bf(acc[mi][ni][v]);
        }
      }
    } else {
      unsigned short* dst = Vtb + (long)hb * HEADP * SEQL;
#pragma unroll
      for (int mi = 0; mi < 4; ++mi) {
        int s0 = m0 + wr * 64 + mi * 16 + g * 4;
#pragma unroll
        for (int ni = 0; ni < 4; ++ni) {
          int p = ni * 16 + r;
          ushort4 pk;
          pk.x = f2bf(acc[mi][ni][0]); pk.y = f2bf(acc[mi][ni][1]);
          pk.z = f2bf(acc[mi][ni][2]); pk.w = f2bf(acc[mi][ni][3]);
          *reinterpret_cast<ushort4*>(dst + (long)p * SEQL + s0) = pk;
        }
      }
    }
  } else {
#pragma unroll
    for (int ni = 0; ni < 4; ++ni) {
      int c = n0 + wc * 64 + ni * 16 + r;
      float bv = bias[c];
#pragma unroll
      for (int mi = 0; mi < 4; ++mi) {
        int s0 = m0 + wr * 64 + mi * 16 + g * 4;
#pragma unroll
        for (int v = 0; v < 4; ++v)
          outf[(long)(s0 + v) * FINALD + c] = acc[mi][ni][v] + bv;
      }
    }
  }
}

// ---- fused sigmoid attention (unchanged from round 3) ------------------
__global__ __launch_bounds__(256) void k_attn(
    const unsigned short* __restrict__ Qb,   // [H][S][P]
    const unsigned short* __restrict__ Kb,   // [H][S][P]
    const unsigned short* __restrict__ Vtb,  // [H][P][S]
    float* __restrict__ P0,                  // partial t-chunk 0 (=d_out)
    float* __restrict__ P1) {                // partial t-chunk 1
  __shared__ char lds[40960];
  int b = blockIdx.x;
  int xcd = b & 7, j = b >> 3;
  int h = xcd + 8 * (j & 1);      // each XCD owns heads {xcd, xcd+8}
  int sblk = (j >> 1) & 31;
  int tc = j >> 6;                // 0..1
  int lane = threadIdx.x & 63, wave = threadIdx.x >> 6;
  int r = lane & 15, g = lane >> 4;
  int q0 = sblk * 64 + wave * 16;
  const unsigned short* Qh = Qb + ((long)h * SEQL + q0) * HEADP;
  const unsigned short* Kh = Kb + (long)h * SEQL * HEADP;
  const unsigned short* Vh = Vtb + (long)h * HEADP * SEQL;

  bf16x8 qf0 = *reinterpret_cast<const bf16x8*>(Qh + (long)r * HEADP + g * 8);
  bf16x8 qf1 = *reinterpret_cast<const bf16x8*>(Qh + (long)r * HEADP + 32 + g * 8);

  f32x4 z4 = {0.f, 0.f, 0.f, 0.f};
  f32x4 oacc[4] = {z4, z4, z4, z4};
  char* slab = lds + 32768 + wave * 2048;
  int swz = (r & 7) << 4;
  const float CLN = -0.02254211001389005f;   // -log2(e)/64

  int sub = lane >> 3, chunk = lane & 7;
  auto stage = [&](int buf, int t0) {
    char* kb = lds + buf * 16384 + wave * 2048;
    char* vb = kb + 8192;
#pragma unroll
    for (int jj = 0; jj < 2; ++jj) {
      int row = wave * 16 + jj * 8 + sub;
      int sw = (chunk ^ (row & 7)) * 8;
      gload16(Kh + (long)(t0 + row) * HEADP + sw, kb + jj * 1024);
      gload16(Vh + (long)row * SEQL + t0 + sw, vb + jj * 1024);
    }
  };

  int tbeg = tc * (SEQL / 2), tend = tbeg + SEQL / 2;
  int cur = 0;
  stage(0, tbeg);
  __syncthreads();
  for (int t0 = tbeg; t0 < tend; t0 += 64) {
    if (t0 + 64 < tend) stage(cur ^ 1, t0 + 64);

    const char* kb = lds + cur * 16384;
    const char* vb = kb + 8192;
    f32x4 s[4] = {z4, z4, z4, z4};
#pragma unroll
    for (int tb = 0; tb < 4; ++tb) {
      const char* krow = kb + (tb * 16 + r) * 128;
      bf16x8 k0 = *reinterpret_cast<const bf16x8*>(krow + ((g ^ (r & 7)) * 16));
      bf16x8 k1 = *reinterpret_cast<const bf16x8*>(krow + (((4 + g) ^ (r & 7)) * 16));
      s[tb] = mfma16(k0, qf0, s[tb]);
      s[tb] = mfma16(k1, qf1, s[tb]);
    }
#pragma unroll
    for (int tb = 0; tb < 4; ++tb) {
      s16x4 pk;
#pragma unroll
      for (int v = 0; v < 4; ++v) {
        float e = __builtin_amdgcn_exp2f(s[tb][v] * CLN);
        pk[v] = (short)f2bf(__builtin_amdgcn_rcpf(1.0f + e));
      }
      *reinterpret_cast<s16x4*>(slab + r * 128 + ((tb * 32 + g * 8) ^ swz)) = pk;
    }
    bf16x8 pa0 = *reinterpret_cast<const bf16x8*>(slab + r * 128 + ((g * 16) ^ swz));
    bf16x8 pa1 = *reinterpret_cast<const bf16x8*>(slab + r * 128 + ((64 + g * 16) ^ swz));
#pragma unroll
    for (int nb = 0; nb < 4; ++nb) {
      const char* vrow = vb + (nb * 16 + r) * 128;
      bf16x8 v0 = *reinterpret_cast<const bf16x8*>(vrow + ((g ^ (r & 7)) * 16));
      bf16x8 v1 = *reinterpret_cast<const bf16x8*>(vrow + (((4 + g) ^ (r & 7)) * 16));
      oacc[nb] = mfma16(pa0, v0, oacc[nb]);
      oacc[nb] = mfma16(pa1, v1, oacc[nb]);
    }
    __syncthreads();
    cur ^= 1;
  }
  float* Po = (tc ? P1 : P0) + ((long)h * SEQL + q0) * HEADP;
#pragma unroll
  for (int nb = 0; nb < 4; ++nb)
#pragma unroll
    for (int v = 0; v < 4; ++v)
      Po[(g * 4 + v) * HEADP + nb * 16 + r] = oacc[nb][v];
}

// ---- reduce partials -> bf16 attn --------------------------------------
__global__ void k_reduce(const float* __restrict__ P0, const float* __restrict__ P1,
                         unsigned short* __restrict__ Ab, int n4) {
  int i = blockIdx.x * blockDim.x + threadIdx.x;
  if (i >= n4) return;
  float4 a = reinterpret_cast<const float4*>(P0)[i];
  float4 b = reinterpret_cast<const float4*>(P1)[i];
  ushort4 o;
  o.x = f2bf(a.x + b.x); o.y = f2bf(a.y + b.y);
  o.z = f2bf(a.z + b.z); o.w = f2bf(a.w + b.w);
  reinterpret_cast<ushort4*>(Ab)[i] = o;
}

// ---- launch -------------------------------------------------------------
extern "C" void kernel_launch(void* const* d_in, const int* in_sizes, int n_in,
                              void* d_out, int out_size, void* d_ws, size_t ws_size,
                              hipStream_t stream) {
  const float* x  = (const float*)d_in[0];
  const float* Qw = (const float*)d_in[1];
  const float* Kw = (const float*)d_in[2];
  const float* Vw = (const float*)d_in[3];
  const float* Wf = (const float*)d_in[4];
  const float* bf = (const float*)d_in[5];
  float* out = (float*)d_out;

  unsigned short* ws  = (unsigned short*)d_ws;
  unsigned short* xb  = ws;                // [2048][1024]       bytes [0,4M)
  unsigned short* Wt  = ws + 2097152;      // [3][16][64][1024]  bytes [4M,10M)  == B^T [3072][1024]
  unsigned short* WfT = ws + 5242880;      // [1024][1024]       bytes [10M,12M)
  unsigned short* Qb  = ws + 6291456;      // [16][2048][64]     bytes [12M,16M)
  unsigned short* Kb  = ws + 8388608;      //                    bytes [16M,20M)
  unsigned short* Vtb = ws + 10485760;     // [16][64][2048]     bytes [20M,24M)
  unsigned short* Ab  = ws + 12582912;     // [16][2048][64]     bytes [24M,28M)
  float* P0 = (float*)d_out;               // partial 0: d_out as scratch (8MB)
  float* P1 = (float*)d_ws;                // partial 1: overlays dead xb/Wt (8MB)

  k_f32_to_bf16<<<2048, 256, 0, stream>>>(x, xb, 524288);
  k_transpose_cvt<<<dim3(16, 1, 16), 256, 0, stream>>>(Qw, Wt,           DMODEL, HEADP);
  k_transpose_cvt<<<dim3(16, 1, 16), 256, 0, stream>>>(Kw, Wt + 1048576, DMODEL, HEADP);
  k_transpose_cvt<<<dim3(16, 1, 16), 256, 0, stream>>>(Vw, Wt + 2097152, DMODEL, HEADP);
  k_transpose_cvt<<<dim3(16, 16, 1), 256, 0, stream>>>(Wf, WfT,          DMODEL, FINALD);
  k_gemm<0><<<dim3(16, 24), 256, 0, stream>>>(xb, Wt, DMODEL, Qb, Kb, Vtb, nullptr, nullptr);
  k_attn<<<1024, 256, 0, stream>>>(Qb, Kb, Vtb, P0, P1);
  k_reduce<<<2048, 256, 0, stream>>>(P0, P1, Ab, 524288);
  k_gemm<1><<<dim3(16, 8), 256, 0, stream>>>(Ab, WfT, DMODEL, nullptr, nullptr, nullptr, bf, out);
}

// Round 5
// 87.204 us; speedup vs baseline: 3.5509x; 1.1532x over previous
//
#include <hip/hip_runtime.h>
#include <hip/hip_bf16.h>

#define SEQL 2048
#define DMODEL 1024
#define NH 16
#define HEADP 64
#define FINALD 1024

using bf16x8 = __attribute__((ext_vector_type(8))) short;   // 8 bf16 (MFMA A/B frag)
using f32x4  = __attribute__((ext_vector_type(4))) float;   // MFMA C/D frag
using s16x4  = __attribute__((ext_vector_type(4))) short;   // 8B LDS write

__device__ __forceinline__ f32x4 mfma16(bf16x8 a, bf16x8 b, f32x4 c) {
  return __builtin_amdgcn_mfma_f32_16x16x32_bf16(a, b, c, 0, 0, 0);
}

__device__ __forceinline__ unsigned short f2bf(float f) {
  return __builtin_bit_cast(unsigned short, __float2bfloat16(f));
}

// async global->LDS, 16B/lane; LDS dest = wave-uniform base + lane*16
__device__ __forceinline__ void gload16(const void* g, void* l) {
  __builtin_amdgcn_global_load_lds(
      (const __attribute__((address_space(1))) void*)g,
      (__attribute__((address_space(3))) void*)l, 16, 0, 0);
}

// ---- x f32 -> bf16 ------------------------------------------------------
__global__ void k_f32_to_bf16(const float* __restrict__ src,
                              unsigned short* __restrict__ dst, int n4) {
  int i = blockIdx.x * blockDim.x + threadIdx.x;
  if (i >= n4) return;
  float4 v = reinterpret_cast<const float4*>(src)[i];
  ushort4 o;
  o.x = f2bf(v.x); o.y = f2bf(v.y); o.z = f2bf(v.z); o.w = f2bf(v.w);
  reinterpret_cast<ushort4*>(dst)[i] = o;
}

// ---- fused weight prep: all 4 transposes in one launch ------------------
// grid (16, 16, 4): z<3 -> Qw/Kw/Vw head transpose (y=head, 1024x64);
//                   z==3 -> W_fin transpose (y=coltile, 1024x1024)
__global__ __launch_bounds__(256) void k_prep(
    const float* __restrict__ Qw, const float* __restrict__ Kw,
    const float* __restrict__ Vw, const float* __restrict__ Wf,
    unsigned short* __restrict__ Wt, unsigned short* __restrict__ WfT) {
  __shared__ float tile[64][65];
  int z = blockIdx.z;
  const float* src; unsigned short* dst;
  int C, tr = blockIdx.x * 64, tc;
  if (z < 3) {
    const float* s3 = (z == 0) ? Qw : (z == 1) ? Kw : Vw;
    src = s3 + (long)blockIdx.y * 65536;                  // head slab [1024][64]
    dst = Wt + (long)z * 1048576 + (long)blockIdx.y * 65536;
    C = 64; tc = 0;
  } else {
    src = Wf; dst = WfT; C = 1024; tc = blockIdx.y * 64;
  }
  const int R = 1024;
  int t = threadIdx.x;
  int r0 = t >> 4, c4 = (t & 15) * 4;
#pragma unroll
  for (int i = 0; i < 4; ++i) {
    int r = i * 16 + r0;
    float4 v = *reinterpret_cast<const float4*>(src + (long)(tr + r) * C + tc + c4);
    tile[r][c4 + 0] = v.x; tile[r][c4 + 1] = v.y;
    tile[r][c4 + 2] = v.z; tile[r][c4 + 3] = v.w;
  }
  __syncthreads();
  int r4 = (t & 15) * 4, cc0 = t >> 4;
#pragma unroll
  for (int i = 0; i < 4; ++i) {
    int c = i * 16 + cc0;
    ushort4 o;
    o.x = f2bf(tile[r4 + 0][c]); o.y = f2bf(tile[r4 + 1][c]);
    o.z = f2bf(tile[r4 + 2][c]); o.w = f2bf(tile[r4 + 3][c]);
    *reinterpret_cast<ushort4*>(dst + (long)(tc + c) * R + tr + r4) = o;
  }
}

// ---- unified LDS-staged GEMM, 128x64 tile (m97 structure) --------------
// C[M,N] = A[M,K] @ Bt[N,K]^T.  BK=32, 4 waves as 2Mx2N (wave-tile 64x32),
// double-buffered LDS (24KB), global_load_lds staging, 2-phase loop.
// EPI=0: QKV epilogue (N=3072; per-block single head; Q/K scatter, V^T)
// EPI=1: f32 + bias epilogue (final GEMM)
template <int EPI>
__global__ __launch_bounds__(256) void k_gemm(
    const unsigned short* __restrict__ A,    // [M][K] bf16
    const unsigned short* __restrict__ Bt,   // [N][K] bf16 (B^T)
    int K,
    unsigned short* __restrict__ Qb,         // [H][S][P]
    unsigned short* __restrict__ Kb,         // [H][S][P]
    unsigned short* __restrict__ Vtb,        // [H][P][S]
    const float* __restrict__ bias,
    float* __restrict__ outf) {              // [S][FINAL]
  __shared__ char lds[24576];                // 2 x (A 8KB + B 4KB)
  int m0 = blockIdx.x * 128, n0 = blockIdx.y * 64;
  int t = threadIdx.x;
  int l = t & 63, w = t >> 6;
  int r = l & 15, g = l >> 4;
  int wr = w >> 1, wc = w & 1;               // wave -> 64x32 quadrant

  const unsigned short* Arow = A + (long)m0 * K;
  const unsigned short* Brow = Bt + (long)n0 * K;
  int rr = l >> 2, c8 = (l & 3) * 8;

  auto stage = [&](int buf, int k0) {
    char* base = lds + buf * 12288;
    char* dA = base + w * 2048;              // A slots 2w,2w+1 (16 rows each)
    char* dB = base + 8192 + w * 1024;       // B slot w
    gload16(Arow + (long)(w * 32 + rr) * K + k0 + c8, dA);
    gload16(Arow + (long)(w * 32 + 16 + rr) * K + k0 + c8, dA + 1024);
    gload16(Brow + (long)(w * 16 + rr) * K + k0 + c8, dB);
  };

  f32x4 acc[4][2] = {};
  int cur = 0, NK = K / 32;
  stage(0, 0);
  __syncthreads();
  for (int kt = 0; kt < NK; ++kt) {
    if (kt + 1 < NK) stage(cur ^ 1, (kt + 1) * 32);   // prefetch next K-tile
    const char* As = lds + cur * 12288;
    const char* Bs = As + 8192;
    bf16x8 af[4], bb[2];
#pragma unroll
    for (int i = 0; i < 4; ++i)
      af[i] = *reinterpret_cast<const bf16x8*>(As + (wr * 64 + i * 16 + r) * 64 + g * 16);
#pragma unroll
    for (int i = 0; i < 2; ++i)
      bb[i] = *reinterpret_cast<const bf16x8*>(Bs + (wc * 32 + i * 16 + r) * 64 + g * 16);
#pragma unroll
    for (int mi = 0; mi < 4; ++mi)
#pragma unroll
      for (int ni = 0; ni < 2; ++ni)
        acc[mi][ni] = mfma16(af[mi], bb[ni], acc[mi][ni]);
    __syncthreads();   // waves done with cur; prefetch (vmcnt) drained
    cur ^= 1;
  }

  if constexpr (EPI == 0) {
    int which = n0 >> 10;
    int hb = (n0 & 1023) >> 6;               // one head per block (BN=64=P)
    if (which < 2) {
      unsigned short* dst = (which == 0 ? Qb : Kb) + (long)hb * SEQL * HEADP;
#pragma unroll
      for (int mi = 0; mi < 4; ++mi) {
        int s0 = m0 + wr * 64 + mi * 16 + g * 4;
#pragma unroll
        for (int ni = 0; ni < 2; ++ni) {
          int p = wc * 32 + ni * 16 + r;
#pragma unroll
          for (int v = 0; v < 4; ++v)
            dst[(long)(s0 + v) * HEADP + p] = f2bf(acc[mi][ni][v]);
        }
      }
    } else {
      unsigned short* dst = Vtb + (long)hb * HEADP * SEQL;
#pragma unroll
      for (int mi = 0; mi < 4; ++mi) {
        int s0 = m0 + wr * 64 + mi * 16 + g * 4;
#pragma unroll
        for (int ni = 0; ni < 2; ++ni) {
          int p = wc * 32 + ni * 16 + r;
          ushort4 pk;
          pk.x = f2bf(acc[mi][ni][0]); pk.y = f2bf(acc[mi][ni][1]);
          pk.z = f2bf(acc[mi][ni][2]); pk.w = f2bf(acc[mi][ni][3]);
          *reinterpret_cast<ushort4*>(dst + (long)p * SEQL + s0) = pk;
        }
      }
    }
  } else {
#pragma unroll
    for (int ni = 0; ni < 2; ++ni) {
      int c = n0 + wc * 32 + ni * 16 + r;
      float bv = bias[c];
#pragma unroll
      for (int mi = 0; mi < 4; ++mi) {
        int s0 = m0 + wr * 64 + mi * 16 + g * 4;
#pragma unroll
        for (int v = 0; v < 4; ++v)
          outf[(long)(s0 + v) * FINALD + c] = acc[mi][ni][v] + bv;
      }
    }
  }
}

// ---- fused sigmoid attention: single-pass t, LDS-staged K/V, dbuf ------
// grid 512, block 256 (4 waves x 16 q-rows). Each XCD owns 2 heads.
__global__ __launch_bounds__(256) void k_attn(
    const unsigned short* __restrict__ Qb,   // [H][S][P]
    const unsigned short* __restrict__ Kb,   // [H][S][P]
    const unsigned short* __restrict__ Vtb,  // [H][P][S]
    unsigned short* __restrict__ Ab) {       // [H][S][P] bf16
  __shared__ char lds[40960];
  int b = blockIdx.x;
  int xcd = b & 7, j = b >> 3;
  int h = (xcd << 1) | (j & 1);   // heads {2*xcd, 2*xcd+1} pinned to xcd
  int sblk = j >> 1;              // 0..31
  int lane = threadIdx.x & 63, wave = threadIdx.x >> 6;
  int r = lane & 15, g = lane >> 4;
  int q0 = sblk * 64 + wave * 16;
  const unsigned short* Qh = Qb + ((long)h * SEQL + q0) * HEADP;
  const unsigned short* Kh = Kb + (long)h * SEQL * HEADP;
  const unsigned short* Vh = Vtb + (long)h * HEADP * SEQL;

  bf16x8 qf0 = *reinterpret_cast<const bf16x8*>(Qh + (long)r * HEADP + g * 8);
  bf16x8 qf1 = *reinterpret_cast<const bf16x8*>(Qh + (long)r * HEADP + 32 + g * 8);

  f32x4 z4 = {0.f, 0.f, 0.f, 0.f};
  f32x4 oacc[4] = {z4, z4, z4, z4};
  char* slab = lds + 32768 + wave * 2048;
  int swz = (r & 7) << 4;
  const float CLN = -0.02254211001389005f;   // -log2(e)/64

  int sub = lane >> 3, chunk = lane & 7;
  auto stage = [&](int buf, int t0) {
    char* kb = lds + buf * 16384 + wave * 2048;
    char* vb = kb + 8192;
#pragma unroll
    for (int jj = 0; jj < 2; ++jj) {
      int row = wave * 16 + jj * 8 + sub;
      int sw = (chunk ^ (row & 7)) * 8;
      gload16(Kh + (long)(t0 + row) * HEADP + sw, kb + jj * 1024);
      gload16(Vh + (long)row * SEQL + t0 + sw, vb + jj * 1024);
    }
  };

  int cur = 0;
  stage(0, 0);
  __syncthreads();
  for (int t0 = 0; t0 < SEQL; t0 += 64) {
    if (t0 + 64 < SEQL) stage(cur ^ 1, t0 + 64);

    const char* kb = lds + cur * 16384;
    const char* vb = kb + 8192;
    // S^T = K @ Q^T : lane holds S[t=tb*16+g*4+v][q=r]
    f32x4 s[4] = {z4, z4, z4, z4};
#pragma unroll
    for (int tb = 0; tb < 4; ++tb) {
      const char* krow = kb + (tb * 16 + r) * 128;
      bf16x8 k0 = *reinterpret_cast<const bf16x8*>(krow + ((g ^ (r & 7)) * 16));
      bf16x8 k1 = *reinterpret_cast<const bf16x8*>(krow + (((4 + g) ^ (r & 7)) * 16));
      s[tb] = mfma16(k0, qf0, s[tb]);
      s[tb] = mfma16(k1, qf1, s[tb]);
    }
    // sigmoid(S/64) -> bf16 -> per-wave slab (8B writes, swizzled)
#pragma unroll
    for (int tb = 0; tb < 4; ++tb) {
      s16x4 pk;
#pragma unroll
      for (int v = 0; v < 4; ++v) {
        float e = __builtin_amdgcn_exp2f(s[tb][v] * CLN);
        pk[v] = (short)f2bf(__builtin_amdgcn_rcpf(1.0f + e));
      }
      *reinterpret_cast<s16x4*>(slab + r * 128 + ((tb * 32 + g * 8) ^ swz)) = pk;
    }
    // PV: A-frags from slab, B-frags from V tile in LDS
    bf16x8 pa0 = *reinterpret_cast<const bf16x8*>(slab + r * 128 + ((g * 16) ^ swz));
    bf16x8 pa1 = *reinterpret_cast<const bf16x8*>(slab + r * 128 + ((64 + g * 16) ^ swz));
#pragma unroll
    for (int nb = 0; nb < 4; ++nb) {
      const char* vrow = vb + (nb * 16 + r) * 128;
      bf16x8 v0 = *reinterpret_cast<const bf16x8*>(vrow + ((g ^ (r & 7)) * 16));
      bf16x8 v1 = *reinterpret_cast<const bf16x8*>(vrow + (((4 + g) ^ (r & 7)) * 16));
      oacc[nb] = mfma16(pa0, v0, oacc[nb]);
      oacc[nb] = mfma16(pa1, v1, oacc[nb]);
    }
    __syncthreads();
    cur ^= 1;
  }
  unsigned short* Oh = Ab + ((long)h * SEQL + q0) * HEADP;
#pragma unroll
  for (int nb = 0; nb < 4; ++nb)
#pragma unroll
    for (int v = 0; v < 4; ++v)
      Oh[(g * 4 + v) * HEADP + nb * 16 + r] = f2bf(oacc[nb][v]);
}

// ---- launch -------------------------------------------------------------
extern "C" void kernel_launch(void* const* d_in, const int* in_sizes, int n_in,
                              void* d_out, int out_size, void* d_ws, size_t ws_size,
                              hipStream_t stream) {
  const float* x  = (const float*)d_in[0];
  const float* Qw = (const float*)d_in[1];
  const float* Kw = (const float*)d_in[2];
  const float* Vw = (const float*)d_in[3];
  const float* Wf = (const float*)d_in[4];
  const float* bf = (const float*)d_in[5];
  float* out = (float*)d_out;

  unsigned short* ws  = (unsigned short*)d_ws;
  unsigned short* xb  = ws;                // [2048][1024]       bytes [0,4M)
  unsigned short* Wt  = ws + 2097152;      // [3][16][64][1024]  bytes [4M,10M)  == B^T [3072][1024]
  unsigned short* WfT = ws + 5242880;      // [1024][1024]       bytes [10M,12M)
  unsigned short* Qb  = ws + 6291456;      // [16][2048][64]     bytes [12M,16M)
  unsigned short* Kb  = ws + 8388608;      //                    bytes [16M,20M)
  unsigned short* Vtb = ws + 10485760;     // [16][64][2048]     bytes [20M,24M)
  unsigned short* Ab  = ws + 12582912;     // [16][2048][64]     bytes [24M,28M)

  k_f32_to_bf16<<<2048, 256, 0, stream>>>(x, xb, 524288);
  k_prep<<<dim3(16, 16, 4), 256, 0, stream>>>(Qw, Kw, Vw, Wf, Wt, WfT);
  k_gemm<0><<<dim3(16, 48), 256, 0, stream>>>(xb, Wt, DMODEL, Qb, Kb, Vtb, nullptr, nullptr);
  k_attn<<<512, 256, 0, stream>>>(Qb, Kb, Vtb, Ab);
  k_gemm<1><<<dim3(16, 16), 256, 0, stream>>>(Ab, WfT, DMODEL, nullptr, nullptr, nullptr, bf, out);
}

// Round 6
// 80.731 us; speedup vs baseline: 3.8355x; 1.0802x over previous
//
#include <hip/hip_runtime.h>
#include <hip/hip_bf16.h>

#define SEQL 2048
#define DMODEL 1024
#define NH 16
#define HEADP 64
#define FINALD 1024

using bf16x8 = __attribute__((ext_vector_type(8))) short;   // 8 bf16 (MFMA A/B frag)
using f32x4  = __attribute__((ext_vector_type(4))) float;   // MFMA C/D frag
using s16x4  = __attribute__((ext_vector_type(4))) short;   // 8B LDS write

__device__ __forceinline__ f32x4 mfma16(bf16x8 a, bf16x8 b, f32x4 c) {
  return __builtin_amdgcn_mfma_f32_16x16x32_bf16(a, b, c, 0, 0, 0);
}

__device__ __forceinline__ unsigned short f2bf(float f) {
  return __builtin_bit_cast(unsigned short, __float2bfloat16(f));
}

// async global->LDS, 16B/lane; LDS dest = wave-uniform base + lane*16
__device__ __forceinline__ void gload16(const void* g, void* l) {
  __builtin_amdgcn_global_load_lds(
      (const __attribute__((address_space(1))) void*)g,
      (__attribute__((address_space(3))) void*)l, 16, 0, 0);
}

// ---- fused prep: weight transposes + x conversion in ONE launch ---------
// grid (16, 16, 5): z<3 -> Qw/Kw/Vw head transpose (y=head, [1024][64]);
//                   z==3 -> W_fin transpose ([1024][1024], y=coltile);
//                   z==4 -> x f32->bf16 (256 blocks x 2048 float4)
__global__ __launch_bounds__(256) void k_prep(
    const float* __restrict__ Qw, const float* __restrict__ Kw,
    const float* __restrict__ Vw, const float* __restrict__ Wf,
    const float* __restrict__ x,
    unsigned short* __restrict__ Wt, unsigned short* __restrict__ WfT,
    unsigned short* __restrict__ xb) {
  __shared__ float tile[64][65];
  int z = blockIdx.z;
  int t = threadIdx.x;
  if (z == 4) {                               // x conversion
    long i0 = ((long)blockIdx.y * 16 + blockIdx.x) * 2048 + t;
#pragma unroll
    for (int k = 0; k < 8; ++k) {
      long i = i0 + k * 256;
      float4 v = reinterpret_cast<const float4*>(x)[i];
      ushort4 o;
      o.x = f2bf(v.x); o.y = f2bf(v.y); o.z = f2bf(v.z); o.w = f2bf(v.w);
      reinterpret_cast<ushort4*>(xb)[i] = o;
    }
    return;
  }
  const float* src; unsigned short* dst;
  int C, tr = blockIdx.x * 64, tc;
  if (z < 3) {
    const float* s3 = (z == 0) ? Qw : (z == 1) ? Kw : Vw;
    src = s3 + (long)blockIdx.y * 65536;                  // head slab [1024][64]
    dst = Wt + (long)z * 1048576 + (long)blockIdx.y * 65536;
    C = 64; tc = 0;
  } else {
    src = Wf; dst = WfT; C = 1024; tc = blockIdx.y * 64;
  }
  const int R = 1024;
  int r0 = t >> 4, c4 = (t & 15) * 4;
#pragma unroll
  for (int i = 0; i < 4; ++i) {
    int r = i * 16 + r0;
    float4 v = *reinterpret_cast<const float4*>(src + (long)(tr + r) * C + tc + c4);
    tile[r][c4 + 0] = v.x; tile[r][c4 + 1] = v.y;
    tile[r][c4 + 2] = v.z; tile[r][c4 + 3] = v.w;
  }
  __syncthreads();
  int r4 = (t & 15) * 4, cc0 = t >> 4;
#pragma unroll
  for (int i = 0; i < 4; ++i) {
    int c = i * 16 + cc0;
    ushort4 o;
    o.x = f2bf(tile[r4 + 0][c]); o.y = f2bf(tile[r4 + 1][c]);
    o.z = f2bf(tile[r4 + 2][c]); o.w = f2bf(tile[r4 + 3][c]);
    *reinterpret_cast<ushort4*>(dst + (long)(tc + c) * R + tr + r4) = o;
  }
}

// ---- unified LDS-staged GEMM, 128x64 tile, BK=64 -----------------------
// C[M,N] = A[M,K] @ Bt[N,K]^T.  4 waves as 2Mx2N (wave-tile 64x32).
// BK=64 staged as TWO BK=32 sub-tiles ([rows][64B] layout, proven 0-conflict),
// 16 MFMA + 12 ds_read_b128 + 6 gload16 per wave per barrier-pair.
// LDS 2 x 24KB dbuf -> 3 blocks/CU.
// EPI=0: QKV epilogue (N=3072; one head per block; Q/K scatter, V^T)
// EPI=1: f32 + bias epilogue (final GEMM)
template <int EPI>
__global__ __launch_bounds__(256) void k_gemm(
    const unsigned short* __restrict__ A,    // [M][K] bf16
    const unsigned short* __restrict__ Bt,   // [N][K] bf16 (B^T)
    int K,
    unsigned short* __restrict__ Qb,         // [H][S][P]
    unsigned short* __restrict__ Kb,         // [H][S][P]
    unsigned short* __restrict__ Vtb,        // [H][P][S]
    const float* __restrict__ bias,
    float* __restrict__ outf) {              // [S][FINAL]
  __shared__ char lds[49152];                // 2 x (A0 8K + A1 8K + B0 4K + B1 4K)
  int m0 = blockIdx.x * 128, n0 = blockIdx.y * 64;
  int t = threadIdx.x;
  int l = t & 63, w = t >> 6;
  int r = l & 15, g = l >> 4;
  int wr = w >> 1, wc = w & 1;               // wave -> 64x32 quadrant

  const unsigned short* Arow = A + (long)m0 * K;
  const unsigned short* Brow = Bt + (long)n0 * K;
  int rr = l >> 2, c8 = (l & 3) * 8;

  auto stage = [&](int buf, int k0) {
    char* base = lds + buf * 24576;
#pragma unroll
    for (int kk = 0; kk < 2; ++kk) {
      char* dA = base + kk * 8192 + w * 2048;      // A sub-tile kk, rows w*32..+31
      char* dB = base + 16384 + kk * 4096 + w * 1024;   // B sub-tile kk, rows w*16..+15
      int kc = k0 + kk * 32 + c8;
      gload16(Arow + (long)(w * 32 + rr) * K + kc, dA);
      gload16(Arow + (long)(w * 32 + 16 + rr) * K + kc, dA + 1024);
      gload16(Brow + (long)(w * 16 + rr) * K + kc, dB);
    }
  };

  f32x4 acc[4][2] = {};
  int cur = 0, NK = K / 64;
  stage(0, 0);
  __syncthreads();
  for (int kt = 0; kt < NK; ++kt) {
    if (kt + 1 < NK) stage(cur ^ 1, (kt + 1) * 64);   // prefetch next K-tile
    const char* base = lds + cur * 24576;
#pragma unroll
    for (int kk = 0; kk < 2; ++kk) {
      const char* As = base + kk * 8192;
      const char* Bs = base + 16384 + kk * 4096;
      bf16x8 af[4], bb[2];
#pragma unroll
      for (int i = 0; i < 4; ++i)
        af[i] = *reinterpret_cast<const bf16x8*>(As + (wr * 64 + i * 16 + r) * 64 + g * 16);
#pragma unroll
      for (int i = 0; i < 2; ++i)
        bb[i] = *reinterpret_cast<const bf16x8*>(Bs + (wc * 32 + i * 16 + r) * 64 + g * 16);
#pragma unroll
      for (int mi = 0; mi < 4; ++mi)
#pragma unroll
        for (int ni = 0; ni < 2; ++ni)
          acc[mi][ni] = mfma16(af[mi], bb[ni], acc[mi][ni]);
    }
    __syncthreads();   // waves done with cur; prefetch (vmcnt) drained
    cur ^= 1;
  }

  if constexpr (EPI == 0) {
    int which = n0 >> 10;
    int hb = (n0 & 1023) >> 6;               // one head per block (BN=64=P)
    if (which < 2) {
      unsigned short* dst = (which == 0 ? Qb : Kb) + (long)hb * SEQL * HEADP;
#pragma unroll
      for (int mi = 0; mi < 4; ++mi) {
        int s0 = m0 + wr * 64 + mi * 16 + g * 4;
#pragma unroll
        for (int ni = 0; ni < 2; ++ni) {
          int p = wc * 32 + ni * 16 + r;
#pragma unroll
          for (int v = 0; v < 4; ++v)
            dst[(long)(s0 + v) * HEADP + p] = f2bf(acc[mi][ni][v]);
        }
      }
    } else {
      unsigned short* dst = Vtb + (long)hb * HEADP * SEQL;
#pragma unroll
      for (int mi = 0; mi < 4; ++mi) {
        int s0 = m0 + wr * 64 + mi * 16 + g * 4;
#pragma unroll
        for (int ni = 0; ni < 2; ++ni) {
          int p = wc * 32 + ni * 16 + r;
          ushort4 pk;
          pk.x = f2bf(acc[mi][ni][0]); pk.y = f2bf(acc[mi][ni][1]);
          pk.z = f2bf(acc[mi][ni][2]); pk.w = f2bf(acc[mi][ni][3]);
          *reinterpret_cast<ushort4*>(dst + (long)p * SEQL + s0) = pk;
        }
      }
    }
  } else {
#pragma unroll
    for (int ni = 0; ni < 2; ++ni) {
      int c = n0 + wc * 32 + ni * 16 + r;
      float bv = bias[c];
#pragma unroll
      for (int mi = 0; mi < 4; ++mi) {
        int s0 = m0 + wr * 64 + mi * 16 + g * 4;
#pragma unroll
        for (int v = 0; v < 4; ++v)
          outf[(long)(s0 + v) * FINALD + c] = acc[mi][ni][v] + bv;
      }
    }
  }
}

// ---- fused sigmoid attention: single-pass t, LDS-staged K/V, dbuf ------
// grid 512, block 256 (4 waves x 16 q-rows). Each XCD owns 2 heads.
__global__ __launch_bounds__(256) void k_attn(
    const unsigned short* __restrict__ Qb,   // [H][S][P]
    const unsigned short* __restrict__ Kb,   // [H][S][P]
    const unsigned short* __restrict__ Vtb,  // [H][P][S]
    unsigned short* __restrict__ Ab) {       // [H][S][P] bf16
  __shared__ char lds[40960];
  int b = blockIdx.x;
  int xcd = b & 7, j = b >> 3;
  int h = (xcd << 1) | (j & 1);   // heads {2*xcd, 2*xcd+1} pinned to xcd
  int sblk = j >> 1;              // 0..31
  int lane = threadIdx.x & 63, wave = threadIdx.x >> 6;
  int r = lane & 15, g = lane >> 4;
  int q0 = sblk * 64 + wave * 16;
  const unsigned short* Qh = Qb + ((long)h * SEQL + q0) * HEADP;
  const unsigned short* Kh = Kb + (long)h * SEQL * HEADP;
  const unsigned short* Vh = Vtb + (long)h * HEADP * SEQL;

  bf16x8 qf0 = *reinterpret_cast<const bf16x8*>(Qh + (long)r * HEADP + g * 8);
  bf16x8 qf1 = *reinterpret_cast<const bf16x8*>(Qh + (long)r * HEADP + 32 + g * 8);

  f32x4 z4 = {0.f, 0.f, 0.f, 0.f};
  f32x4 oacc[4] = {z4, z4, z4, z4};
  char* slab = lds + 32768 + wave * 2048;
  int swz = (r & 7) << 4;
  const float CLN = -0.02254211001389005f;   // -log2(e)/64

  int sub = lane >> 3, chunk = lane & 7;
  auto stage = [&](int buf, int t0) {
    char* kb = lds + buf * 16384 + wave * 2048;
    char* vb = kb + 8192;
#pragma unroll
    for (int jj = 0; jj < 2; ++jj) {
      int row = wave * 16 + jj * 8 + sub;
      int sw = (chunk ^ (row & 7)) * 8;
      gload16(Kh + (long)(t0 + row) * HEADP + sw, kb + jj * 1024);
      gload16(Vh + (long)row * SEQL + t0 + sw, vb + jj * 1024);
    }
  };

  int cur = 0;
  stage(0, 0);
  __syncthreads();
  for (int t0 = 0; t0 < SEQL; t0 += 64) {
    if (t0 + 64 < SEQL) stage(cur ^ 1, t0 + 64);

    const char* kb = lds + cur * 16384;
    const char* vb = kb + 8192;
    // S^T = K @ Q^T : lane holds S[t=tb*16+g*4+v][q=r]
    f32x4 s[4] = {z4, z4, z4, z4};
    __builtin_amdgcn_s_setprio(1);
#pragma unroll
    for (int tb = 0; tb < 4; ++tb) {
      const char* krow = kb + (tb * 16 + r) * 128;
      bf16x8 k0 = *reinterpret_cast<const bf16x8*>(krow + ((g ^ (r & 7)) * 16));
      bf16x8 k1 = *reinterpret_cast<const bf16x8*>(krow + (((4 + g) ^ (r & 7)) * 16));
      s[tb] = mfma16(k0, qf0, s[tb]);
      s[tb] = mfma16(k1, qf1, s[tb]);
    }
    __builtin_amdgcn_s_setprio(0);
    // sigmoid(S/64) -> bf16 -> per-wave slab (8B writes, swizzled)
#pragma unroll
    for (int tb = 0; tb < 4; ++tb) {
      s16x4 pk;
#pragma unroll
      for (int v = 0; v < 4; ++v) {
        float e = __builtin_amdgcn_exp2f(s[tb][v] * CLN);
        pk[v] = (short)f2bf(__builtin_amdgcn_rcpf(1.0f + e));
      }
      *reinterpret_cast<s16x4*>(slab + r * 128 + ((tb * 32 + g * 8) ^ swz)) = pk;
    }
    // PV: A-frags from slab, B-frags from V tile in LDS
    bf16x8 pa0 = *reinterpret_cast<const bf16x8*>(slab + r * 128 + ((g * 16) ^ swz));
    bf16x8 pa1 = *reinterpret_cast<const bf16x8*>(slab + r * 128 + ((64 + g * 16) ^ swz));
    __builtin_amdgcn_s_setprio(1);
#pragma unroll
    for (int nb = 0; nb < 4; ++nb) {
      const char* vrow = vb + (nb * 16 + r) * 128;
      bf16x8 v0 = *reinterpret_cast<const bf16x8*>(vrow + ((g ^ (r & 7)) * 16));
      bf16x8 v1 = *reinterpret_cast<const bf16x8*>(vrow + (((4 + g) ^ (r & 7)) * 16));
      oacc[nb] = mfma16(pa0, v0, oacc[nb]);
      oacc[nb] = mfma16(pa1, v1, oacc[nb]);
    }
    __builtin_amdgcn_s_setprio(0);
    __syncthreads();
    cur ^= 1;
  }
  unsigned short* Oh = Ab + ((long)h * SEQL + q0) * HEADP;
#pragma unroll
  for (int nb = 0; nb < 4; ++nb)
#pragma unroll
    for (int v = 0; v < 4; ++v)
      Oh[(g * 4 + v) * HEADP + nb * 16 + r] = f2bf(oacc[nb][v]);
}

// ---- launch -------------------------------------------------------------
extern "C" void kernel_launch(void* const* d_in, const int* in_sizes, int n_in,
                              void* d_out, int out_size, void* d_ws, size_t ws_size,
                              hipStream_t stream) {
  const float* x  = (const float*)d_in[0];
  const float* Qw = (const float*)d_in[1];
  const float* Kw = (const float*)d_in[2];
  const float* Vw = (const float*)d_in[3];
  const float* Wf = (const float*)d_in[4];
  const float* bf = (const float*)d_in[5];
  float* out = (float*)d_out;

  unsigned short* ws  = (unsigned short*)d_ws;
  unsigned short* xb  = ws;                // [2048][1024]       bytes [0,4M)
  unsigned short* Wt  = ws + 2097152;      // [3][16][64][1024]  bytes [4M,10M)  == B^T [3072][1024]
  unsigned short* WfT = ws + 5242880;      // [1024][1024]       bytes [10M,12M)
  unsigned short* Qb  = ws + 6291456;      // [16][2048][64]     bytes [12M,16M)
  unsigned short* Kb  = ws + 8388608;      //                    bytes [16M,20M)
  unsigned short* Vtb = ws + 10485760;     // [16][64][2048]     bytes [20M,24M)
  unsigned short* Ab  = ws + 12582912;     // [16][2048][64]     bytes [24M,28M)

  k_prep<<<dim3(16, 16, 5), 256, 0, stream>>>(Qw, Kw, Vw, Wf, x, Wt, WfT, xb);
  k_gemm<0><<<dim3(16, 48), 256, 0, stream>>>(xb, Wt, DMODEL, Qb, Kb, Vtb, nullptr, nullptr);
  k_attn<<<512, 256, 0, stream>>>(Qb, Kb, Vtb, Ab);
  k_gemm<1><<<dim3(16, 16), 256, 0, stream>>>(Ab, WfT, DMODEL, nullptr, nullptr, nullptr, bf, out);
}

// Round 7
// 79.126 us; speedup vs baseline: 3.9133x; 1.0203x over previous
//
#include <hip/hip_runtime.h>
#include <hip/hip_bf16.h>

#define SEQL 2048
#define DMODEL 1024
#define NH 16
#define HEADP 64
#define FINALD 1024

using bf16x8 = __attribute__((ext_vector_type(8))) short;   // 8 bf16 (MFMA A/B frag)
using f32x4  = __attribute__((ext_vector_type(4))) float;   // MFMA C/D frag
using s16x4  = __attribute__((ext_vector_type(4))) short;   // 8B LDS write

__device__ __forceinline__ f32x4 mfma16(bf16x8 a, bf16x8 b, f32x4 c) {
  return __builtin_amdgcn_mfma_f32_16x16x32_bf16(a, b, c, 0, 0, 0);
}

__device__ __forceinline__ unsigned short f2bf(float f) {
  return __builtin_bit_cast(unsigned short, __float2bfloat16(f));
}

// async global->LDS, 16B/lane; LDS dest = wave-uniform base + lane*16
__device__ __forceinline__ void gload16(const void* g, void* l) {
  __builtin_amdgcn_global_load_lds(
      (const __attribute__((address_space(1))) void*)g,
      (__attribute__((address_space(3))) void*)l, 16, 0, 0);
}

// ---- fused prep: weight transposes + x conversion in ONE launch ---------
// grid (16, 16, 5): z<3 -> Qw/Kw/Vw head transpose (y=head, [1024][64]);
//                   z==3 -> W_fin transpose ([1024][1024], y=coltile);
//                   z==4 -> x f32->bf16 (256 blocks x 2048 float4)
__global__ __launch_bounds__(256) void k_prep(
    const float* __restrict__ Qw, const float* __restrict__ Kw,
    const float* __restrict__ Vw, const float* __restrict__ Wf,
    const float* __restrict__ x,
    unsigned short* __restrict__ Wt, unsigned short* __restrict__ WfT,
    unsigned short* __restrict__ xb) {
  __shared__ float tile[64][65];
  int z = blockIdx.z;
  int t = threadIdx.x;
  if (z == 4) {                               // x conversion
    long i0 = ((long)blockIdx.y * 16 + blockIdx.x) * 2048 + t;
#pragma unroll
    for (int k = 0; k < 8; ++k) {
      long i = i0 + k * 256;
      float4 v = reinterpret_cast<const float4*>(x)[i];
      ushort4 o;
      o.x = f2bf(v.x); o.y = f2bf(v.y); o.z = f2bf(v.z); o.w = f2bf(v.w);
      reinterpret_cast<ushort4*>(xb)[i] = o;
    }
    return;
  }
  const float* src; unsigned short* dst;
  int C, tr = blockIdx.x * 64, tc;
  if (z < 3) {
    const float* s3 = (z == 0) ? Qw : (z == 1) ? Kw : Vw;
    src = s3 + (long)blockIdx.y * 65536;                  // head slab [1024][64]
    dst = Wt + (long)z * 1048576 + (long)blockIdx.y * 65536;
    C = 64; tc = 0;
  } else {
    src = Wf; dst = WfT; C = 1024; tc = blockIdx.y * 64;
  }
  const int R = 1024;
  int r0 = t >> 4, c4 = (t & 15) * 4;
#pragma unroll
  for (int i = 0; i < 4; ++i) {
    int r = i * 16 + r0;
    float4 v = *reinterpret_cast<const float4*>(src + (long)(tr + r) * C + tc + c4);
    tile[r][c4 + 0] = v.x; tile[r][c4 + 1] = v.y;
    tile[r][c4 + 2] = v.z; tile[r][c4 + 3] = v.w;
  }
  __syncthreads();
  int r4 = (t & 15) * 4, cc0 = t >> 4;
#pragma unroll
  for (int i = 0; i < 4; ++i) {
    int c = i * 16 + cc0;
    ushort4 o;
    o.x = f2bf(tile[r4 + 0][c]); o.y = f2bf(tile[r4 + 1][c]);
    o.z = f2bf(tile[r4 + 2][c]); o.w = f2bf(tile[r4 + 3][c]);
    *reinterpret_cast<ushort4*>(dst + (long)(tc + c) * R + tr + r4) = o;
  }
}

// ---- unified LDS-staged GEMM, 128x64 tile, BK=64 -----------------------
// C[M,N] = A[M,K] @ Bt[N,K]^T.  4 waves as 2Mx2N (wave-tile 64x32).
// BK=64 as TWO BK=32 sub-tiles, [rows][64B] LDS layout with k-chunk
// XOR-swizzle chunk ^= (row>>1)&3 applied BOTH on the pre-swizzled global
// source (LDS dest linear, per global_load_lds rules) and on frag ds_reads
// -> 2-way banks (free) instead of 8-way (~2.7x).
// Bijective XCD swizzle on the flattened grid (total % 8 == 0): each XCD
// owns a contiguous n-chunk (A L2-resident, small B-chunk).
// EPI=0: QKV epilogue (N=3072; one head per block; Q/K scatter, V^T)
// EPI=1: f32 + bias epilogue (final GEMM)
template <int EPI>
__global__ __launch_bounds__(256) void k_gemm(
    const unsigned short* __restrict__ A,    // [M][K] bf16
    const unsigned short* __restrict__ Bt,   // [N][K] bf16 (B^T)
    int K,
    unsigned short* __restrict__ Qb,         // [H][S][P]
    unsigned short* __restrict__ Kb,         // [H][S][P]
    unsigned short* __restrict__ Vtb,        // [H][P][S]
    const float* __restrict__ bias,
    float* __restrict__ outf) {              // [S][FINAL]
  __shared__ char lds[49152];                // 2 x (A0 8K + A1 8K + B0 4K + B1 4K)
  // XCD-aware remap: orig dispatch order is x-fastest; orig%8 -> XCD.
  int flat = blockIdx.y * 16 + blockIdx.x;   // gridDim.x == 16 always here
  int cpx = (gridDim.x * gridDim.y) >> 3;
  flat = (flat & 7) * cpx + (flat >> 3);     // XCD k owns contiguous chunk
  int m0 = (flat & 15) << 7, n0 = (flat >> 4) * 64;
  int t = threadIdx.x;
  int l = t & 63, w = t >> 6;
  int r = l & 15, g = l >> 4;
  int wr = w >> 1, wc = w & 1;               // wave -> 64x32 quadrant

  const unsigned short* Arow = A + (long)m0 * K;
  const unsigned short* Brow = Bt + (long)n0 * K;
  int rr = l >> 2;
  int c8s = (((l & 3) ^ ((l >> 3) & 3)) * 8);   // pre-swizzled k-chunk (elems)

  auto stage = [&](int buf, int k0) {
    char* base = lds + buf * 24576;
#pragma unroll
    for (int kk = 0; kk < 2; ++kk) {
      char* dA = base + kk * 8192 + w * 2048;      // A sub-tile kk, rows w*32..+31
      char* dB = base + 16384 + kk * 4096 + w * 1024;   // B sub-tile kk, rows w*16..+15
      int kc = k0 + kk * 32 + c8s;
      gload16(Arow + (long)(w * 32 + rr) * K + kc, dA);
      gload16(Arow + (long)(w * 32 + 16 + rr) * K + kc, dA + 1024);
      gload16(Brow + (long)(w * 16 + rr) * K + kc, dB);
    }
  };

  int xk = (r >> 1) & 3;                     // frag-read xor (row>>1)&3 == (r>>1)&3
  f32x4 acc[4][2] = {};
  int cur = 0, NK = K / 64;
  stage(0, 0);
  __syncthreads();
  for (int kt = 0; kt < NK; ++kt) {
    if (kt + 1 < NK) stage(cur ^ 1, (kt + 1) * 64);   // prefetch next K-tile
    const char* base = lds + cur * 24576;
#pragma unroll
    for (int kk = 0; kk < 2; ++kk) {
      const char* As = base + kk * 8192;
      const char* Bs = base + 16384 + kk * 4096;
      bf16x8 af[4], bb[2];
#pragma unroll
      for (int i = 0; i < 4; ++i)
        af[i] = *reinterpret_cast<const bf16x8*>(As + (wr * 64 + i * 16 + r) * 64 + ((g ^ xk) * 16));
#pragma unroll
      for (int i = 0; i < 2; ++i)
        bb[i] = *reinterpret_cast<const bf16x8*>(Bs + (wc * 32 + i * 16 + r) * 64 + ((g ^ xk) * 16));
#pragma unroll
      for (int mi = 0; mi < 4; ++mi)
#pragma unroll
        for (int ni = 0; ni < 2; ++ni)
          acc[mi][ni] = mfma16(af[mi], bb[ni], acc[mi][ni]);
    }
    __syncthreads();   // waves done with cur; prefetch (vmcnt) drained
    cur ^= 1;
  }

  if constexpr (EPI == 0) {
    int which = n0 >> 10;
    int hb = (n0 & 1023) >> 6;               // one head per block (BN=64=P)
    if (which < 2) {
      unsigned short* dst = (which == 0 ? Qb : Kb) + (long)hb * SEQL * HEADP;
#pragma unroll
      for (int mi = 0; mi < 4; ++mi) {
        int s0 = m0 + wr * 64 + mi * 16 + g * 4;
#pragma unroll
        for (int ni = 0; ni < 2; ++ni) {
          int p = wc * 32 + ni * 16 + r;
#pragma unroll
          for (int v = 0; v < 4; ++v)
            dst[(long)(s0 + v) * HEADP + p] = f2bf(acc[mi][ni][v]);
        }
      }
    } else {
      unsigned short* dst = Vtb + (long)hb * HEADP * SEQL;
#pragma unroll
      for (int mi = 0; mi < 4; ++mi) {
        int s0 = m0 + wr * 64 + mi * 16 + g * 4;
#pragma unroll
        for (int ni = 0; ni < 2; ++ni) {
          int p = wc * 32 + ni * 16 + r;
          ushort4 pk;
          pk.x = f2bf(acc[mi][ni][0]); pk.y = f2bf(acc[mi][ni][1]);
          pk.z = f2bf(acc[mi][ni][2]); pk.w = f2bf(acc[mi][ni][3]);
          *reinterpret_cast<ushort4*>(dst + (long)p * SEQL + s0) = pk;
        }
      }
    }
  } else {
#pragma unroll
    for (int ni = 0; ni < 2; ++ni) {
      int c = n0 + wc * 32 + ni * 16 + r;
      float bv = bias[c];
#pragma unroll
      for (int mi = 0; mi < 4; ++mi) {
        int s0 = m0 + wr * 64 + mi * 16 + g * 4;
#pragma unroll
        for (int v = 0; v < 4; ++v)
          outf[(long)(s0 + v) * FINALD + c] = acc[mi][ni][v] + bv;
      }
    }
  }
}

// ---- fused sigmoid attention: single-pass t, LDS-staged K/V, dbuf ------
// grid 512, block 256 (4 waves x 16 q-rows). Each XCD owns 2 heads.
__global__ __launch_bounds__(256) void k_attn(
    const unsigned short* __restrict__ Qb,   // [H][S][P]
    const unsigned short* __restrict__ Kb,   // [H][S][P]
    const unsigned short* __restrict__ Vtb,  // [H][P][S]
    unsigned short* __restrict__ Ab) {       // [H][S][P] bf16
  __shared__ char lds[40960];
  int b = blockIdx.x;
  int xcd = b & 7, j = b >> 3;
  int h = (xcd << 1) | (j & 1);   // heads {2*xcd, 2*xcd+1} pinned to xcd
  int sblk = j >> 1;              // 0..31
  int lane = threadIdx.x & 63, wave = threadIdx.x >> 6;
  int r = lane & 15, g = lane >> 4;
  int q0 = sblk * 64 + wave * 16;
  const unsigned short* Qh = Qb + ((long)h * SEQL + q0) * HEADP;
  const unsigned short* Kh = Kb + (long)h * SEQL * HEADP;
  const unsigned short* Vh = Vtb + (long)h * HEADP * SEQL;

  bf16x8 qf0 = *reinterpret_cast<const bf16x8*>(Qh + (long)r * HEADP + g * 8);
  bf16x8 qf1 = *reinterpret_cast<const bf16x8*>(Qh + (long)r * HEADP + 32 + g * 8);

  f32x4 z4 = {0.f, 0.f, 0.f, 0.f};
  f32x4 oacc[4] = {z4, z4, z4, z4};
  char* slab = lds + 32768 + wave * 2048;
  int swz = (r & 7) << 4;
  const float CLN = -0.02254211001389005f;   // -log2(e)/64

  int sub = lane >> 3, chunk = lane & 7;
  auto stage = [&](int buf, int t0) {
    char* kb = lds + buf * 16384 + wave * 2048;
    char* vb = kb + 8192;
#pragma unroll
    for (int jj = 0; jj < 2; ++jj) {
      int row = wave * 16 + jj * 8 + sub;
      int sw = (chunk ^ (row & 7)) * 8;
      gload16(Kh + (long)(t0 + row) * HEADP + sw, kb + jj * 1024);
      gload16(Vh + (long)row * SEQL + t0 + sw, vb + jj * 1024);
    }
  };

  int cur = 0;
  stage(0, 0);
  __syncthreads();
  for (int t0 = 0; t0 < SEQL; t0 += 64) {
    if (t0 + 64 < SEQL) stage(cur ^ 1, t0 + 64);

    const char* kb = lds + cur * 16384;
    const char* vb = kb + 8192;
    // S^T = K @ Q^T : lane holds S[t=tb*16+g*4+v][q=r]
    f32x4 s[4] = {z4, z4, z4, z4};
    __builtin_amdgcn_s_setprio(1);
#pragma unroll
    for (int tb = 0; tb < 4; ++tb) {
      const char* krow = kb + (tb * 16 + r) * 128;
      bf16x8 k0 = *reinterpret_cast<const bf16x8*>(krow + ((g ^ (r & 7)) * 16));
      bf16x8 k1 = *reinterpret_cast<const bf16x8*>(krow + (((4 + g) ^ (r & 7)) * 16));
      s[tb] = mfma16(k0, qf0, s[tb]);
      s[tb] = mfma16(k1, qf1, s[tb]);
    }
    __builtin_amdgcn_s_setprio(0);
    // sigmoid(S/64) -> bf16 -> per-wave slab (8B writes, swizzled)
#pragma unroll
    for (int tb = 0; tb < 4; ++tb) {
      s16x4 pk;
#pragma unroll
      for (int v = 0; v < 4; ++v) {
        float e = __builtin_amdgcn_exp2f(s[tb][v] * CLN);
        pk[v] = (short)f2bf(__builtin_amdgcn_rcpf(1.0f + e));
      }
      *reinterpret_cast<s16x4*>(slab + r * 128 + ((tb * 32 + g * 8) ^ swz)) = pk;
    }
    // PV: A-frags from slab, B-frags from V tile in LDS
    bf16x8 pa0 = *reinterpret_cast<const bf16x8*>(slab + r * 128 + ((g * 16) ^ swz));
    bf16x8 pa1 = *reinterpret_cast<const bf16x8*>(slab + r * 128 + ((64 + g * 16) ^ swz));
    __builtin_amdgcn_s_setprio(1);
#pragma unroll
    for (int nb = 0; nb < 4; ++nb) {
      const char* vrow = vb + (nb * 16 + r) * 128;
      bf16x8 v0 = *reinterpret_cast<const bf16x8*>(vrow + ((g ^ (r & 7)) * 16));
      bf16x8 v1 = *reinterpret_cast<const bf16x8*>(vrow + (((4 + g) ^ (r & 7)) * 16));
      oacc[nb] = mfma16(pa0, v0, oacc[nb]);
      oacc[nb] = mfma16(pa1, v1, oacc[nb]);
    }
    __builtin_amdgcn_s_setprio(0);
    __syncthreads();
    cur ^= 1;
  }
  unsigned short* Oh = Ab + ((long)h * SEQL + q0) * HEADP;
#pragma unroll
  for (int nb = 0; nb < 4; ++nb)
#pragma unroll
    for (int v = 0; v < 4; ++v)
      Oh[(g * 4 + v) * HEADP + nb * 16 + r] = f2bf(oacc[nb][v]);
}

// ---- launch -------------------------------------------------------------
extern "C" void kernel_launch(void* const* d_in, const int* in_sizes, int n_in,
                              void* d_out, int out_size, void* d_ws, size_t ws_size,
                              hipStream_t stream) {
  const float* x  = (const float*)d_in[0];
  const float* Qw = (const float*)d_in[1];
  const float* Kw = (const float*)d_in[2];
  const float* Vw = (const float*)d_in[3];
  const float* Wf = (const float*)d_in[4];
  const float* bf = (const float*)d_in[5];
  float* out = (float*)d_out;

  unsigned short* ws  = (unsigned short*)d_ws;
  unsigned short* xb  = ws;                // [2048][1024]       bytes [0,4M)
  unsigned short* Wt  = ws + 2097152;      // [3][16][64][1024]  bytes [4M,10M)  == B^T [3072][1024]
  unsigned short* WfT = ws + 5242880;      // [1024][1024]       bytes [10M,12M)
  unsigned short* Qb  = ws + 6291456;      // [16][2048][64]     bytes [12M,16M)
  unsigned short* Kb  = ws + 8388608;      //                    bytes [16M,20M)
  unsigned short* Vtb = ws + 10485760;     // [16][64][2048]     bytes [20M,24M)
  unsigned short* Ab  = ws + 12582912;     // [16][2048][64]     bytes [24M,28M)

  k_prep<<<dim3(16, 16, 5), 256, 0, stream>>>(Qw, Kw, Vw, Wf, x, Wt, WfT, xb);
  k_gemm<0><<<dim3(16, 48), 256, 0, stream>>>(xb, Wt, DMODEL, Qb, Kb, Vtb, nullptr, nullptr);
  k_attn<<<512, 256, 0, stream>>>(Qb, Kb, Vtb, Ab);
  k_gemm<1><<<dim3(16, 16), 256, 0, stream>>>(Ab, WfT, DMODEL, nullptr, nullptr, nullptr, bf, out);
}

// Round 8
// 77.721 us; speedup vs baseline: 3.9841x; 1.0181x over previous
//
#include <hip/hip_runtime.h>
#include <hip/hip_bf16.h>

#define SEQL 2048
#define DMODEL 1024
#define NH 16
#define HEADP 64
#define FINALD 1024

using bf16x8 = __attribute__((ext_vector_type(8))) short;   // 8 bf16 (MFMA A/B frag)
using f32x4  = __attribute__((ext_vector_type(4))) float;   // MFMA C/D frag
using s16x4  = __attribute__((ext_vector_type(4))) short;   // 8B LDS write

// counted vmcnt wait: loads stay in flight across barriers (T4)
#define WAITV(N) asm volatile("s_waitcnt vmcnt(" #N ")" ::: "memory")

__device__ __forceinline__ f32x4 mfma16(bf16x8 a, bf16x8 b, f32x4 c) {
  return __builtin_amdgcn_mfma_f32_16x16x32_bf16(a, b, c, 0, 0, 0);
}

__device__ __forceinline__ unsigned short f2bf(float f) {
  return __builtin_bit_cast(unsigned short, __float2bfloat16(f));
}

// async global->LDS, 16B/lane; LDS dest = wave-uniform base + lane*16
__device__ __forceinline__ void gload16(const void* g, void* l) {
  __builtin_amdgcn_global_load_lds(
      (const __attribute__((address_space(1))) void*)g,
      (__attribute__((address_space(3))) void*)l, 16, 0, 0);
}

// ---- fused prep: weight transposes + x conversion in ONE launch ---------
// grid (16, 16, 5): z<3 -> Qw/Kw/Vw head transpose (y=head, [1024][64]);
//                   z==3 -> W_fin transpose ([1024][1024], y=coltile);
//                   z==4 -> x f32->bf16 (256 blocks x 2048 float4)
__global__ __launch_bounds__(256) void k_prep(
    const float* __restrict__ Qw, const float* __restrict__ Kw,
    const float* __restrict__ Vw, const float* __restrict__ Wf,
    const float* __restrict__ x,
    unsigned short* __restrict__ Wt, unsigned short* __restrict__ WfT,
    unsigned short* __restrict__ xb) {
  __shared__ float tile[64][65];
  int z = blockIdx.z;
  int t = threadIdx.x;
  if (z == 4) {                               // x conversion
    long i0 = ((long)blockIdx.y * 16 + blockIdx.x) * 2048 + t;
#pragma unroll
    for (int k = 0; k < 8; ++k) {
      long i = i0 + k * 256;
      float4 v = reinterpret_cast<const float4*>(x)[i];
      ushort4 o;
      o.x = f2bf(v.x); o.y = f2bf(v.y); o.z = f2bf(v.z); o.w = f2bf(v.w);
      reinterpret_cast<ushort4*>(xb)[i] = o;
    }
    return;
  }
  const float* src; unsigned short* dst;
  int C, tr = blockIdx.x * 64, tc;
  if (z < 3) {
    const float* s3 = (z == 0) ? Qw : (z == 1) ? Kw : Vw;
    src = s3 + (long)blockIdx.y * 65536;                  // head slab [1024][64]
    dst = Wt + (long)z * 1048576 + (long)blockIdx.y * 65536;
    C = 64; tc = 0;
  } else {
    src = Wf; dst = WfT; C = 1024; tc = blockIdx.y * 64;
  }
  const int R = 1024;
  int r0 = t >> 4, c4 = (t & 15) * 4;
#pragma unroll
  for (int i = 0; i < 4; ++i) {
    int r = i * 16 + r0;
    float4 v = *reinterpret_cast<const float4*>(src + (long)(tr + r) * C + tc + c4);
    tile[r][c4 + 0] = v.x; tile[r][c4 + 1] = v.y;
    tile[r][c4 + 2] = v.z; tile[r][c4 + 3] = v.w;
  }
  __syncthreads();
  int r4 = (t & 15) * 4, cc0 = t >> 4;
#pragma unroll
  for (int i = 0; i < 4; ++i) {
    int c = i * 16 + cc0;
    ushort4 o;
    o.x = f2bf(tile[r4 + 0][c]); o.y = f2bf(tile[r4 + 1][c]);
    o.z = f2bf(tile[r4 + 2][c]); o.w = f2bf(tile[r4 + 3][c]);
    *reinterpret_cast<ushort4*>(dst + (long)(tc + c) * R + tr + r4) = o;
  }
}

// ---- unified LDS-staged GEMM, 128x64 tile, BK=64, counted-vmcnt --------
// C[M,N] = A[M,K] @ Bt[N,K]^T.  4 waves as 2Mx2N (wave-tile 64x32).
// BK=64 as TWO BK=32 sub-tiles, [rows][64B] LDS, k-chunk XOR swizzle
// (both-sides, rule #21).  Pipeline: raw barrier A (readers done) ->
// stage next -> vmcnt(6) (cur landed, prefetch spans barrier) ->
// raw barrier B -> ds_read+MFMA.  Never drains vmcnt to 0 mid-loop (T4).
// Bijective XCD swizzle on the flattened grid.
// EPI=0: QKV epilogue; EPI=1: f32 + bias epilogue.
template <int EPI>
__global__ __launch_bounds__(256) void k_gemm(
    const unsigned short* __restrict__ A,    // [M][K] bf16
    const unsigned short* __restrict__ Bt,   // [N][K] bf16 (B^T)
    int K,
    unsigned short* __restrict__ Qb,         // [H][S][P]
    unsigned short* __restrict__ Kb,         // [H][S][P]
    unsigned short* __restrict__ Vtb,        // [H][P][S]
    const float* __restrict__ bias,
    float* __restrict__ outf) {              // [S][FINAL]
  __shared__ char lds[49152];                // 2 x (A0 8K + A1 8K + B0 4K + B1 4K)
  int flat = blockIdx.y * 16 + blockIdx.x;   // gridDim.x == 16 always here
  int cpx = (gridDim.x * gridDim.y) >> 3;
  flat = (flat & 7) * cpx + (flat >> 3);     // XCD k owns contiguous chunk
  int m0 = (flat & 15) << 7, n0 = (flat >> 4) * 64;
  int t = threadIdx.x;
  int l = t & 63, w = t >> 6;
  int r = l & 15, g = l >> 4;
  int wr = w >> 1, wc = w & 1;               // wave -> 64x32 quadrant

  const unsigned short* Arow = A + (long)m0 * K;
  const unsigned short* Brow = Bt + (long)n0 * K;
  int rr = l >> 2;
  int c8s = (((l & 3) ^ ((l >> 3) & 3)) * 8);   // pre-swizzled k-chunk (elems)

  auto stage = [&](int buf, int k0) {
    char* base = lds + buf * 24576;
#pragma unroll
    for (int kk = 0; kk < 2; ++kk) {
      char* dA = base + kk * 8192 + w * 2048;
      char* dB = base + 16384 + kk * 4096 + w * 1024;
      int kc = k0 + kk * 32 + c8s;
      gload16(Arow + (long)(w * 32 + rr) * K + kc, dA);
      gload16(Arow + (long)(w * 32 + 16 + rr) * K + kc, dA + 1024);
      gload16(Brow + (long)(w * 16 + rr) * K + kc, dB);
    }
  };

  int xk = (r >> 1) & 3;                     // frag-read xor
  f32x4 acc[4][2] = {};
  int cur = 0, NK = K / 64;
  stage(0, 0);                               // 6 loads in flight
  for (int kt = 0; kt < NK; ++kt) {
    __builtin_amdgcn_s_barrier();            // A: all done reading buf cur^1
    if (kt + 1 < NK) {
      stage(cur ^ 1, (kt + 1) * 64);         // 6 more loads (12 outstanding)
      WAITV(6);                              // cur's loads landed; next stays in flight
    } else {
      WAITV(0);
    }
    __builtin_amdgcn_s_barrier();            // B: everyone's cur loads landed
    __builtin_amdgcn_sched_barrier(0);
    const char* base = lds + cur * 24576;
#pragma unroll
    for (int kk = 0; kk < 2; ++kk) {
      const char* As = base + kk * 8192;
      const char* Bs = base + 16384 + kk * 4096;
      bf16x8 af[4], bb[2];
#pragma unroll
      for (int i = 0; i < 4; ++i)
        af[i] = *reinterpret_cast<const bf16x8*>(As + (wr * 64 + i * 16 + r) * 64 + ((g ^ xk) * 16));
#pragma unroll
      for (int i = 0; i < 2; ++i)
        bb[i] = *reinterpret_cast<const bf16x8*>(Bs + (wc * 32 + i * 16 + r) * 64 + ((g ^ xk) * 16));
#pragma unroll
      for (int mi = 0; mi < 4; ++mi)
#pragma unroll
        for (int ni = 0; ni < 2; ++ni)
          acc[mi][ni] = mfma16(af[mi], bb[ni], acc[mi][ni]);
    }
    cur ^= 1;
  }

  if constexpr (EPI == 0) {
    int which = n0 >> 10;
    int hb = (n0 & 1023) >> 6;               // one head per block (BN=64=P)
    if (which < 2) {
      unsigned short* dst = (which == 0 ? Qb : Kb) + (long)hb * SEQL * HEADP;
#pragma unroll
      for (int mi = 0; mi < 4; ++mi) {
        int s0 = m0 + wr * 64 + mi * 16 + g * 4;
#pragma unroll
        for (int ni = 0; ni < 2; ++ni) {
          int p = wc * 32 + ni * 16 + r;
#pragma unroll
          for (int v = 0; v < 4; ++v)
            dst[(long)(s0 + v) * HEADP + p] = f2bf(acc[mi][ni][v]);
        }
      }
    } else {
      unsigned short* dst = Vtb + (long)hb * HEADP * SEQL;
#pragma unroll
      for (int mi = 0; mi < 4; ++mi) {
        int s0 = m0 + wr * 64 + mi * 16 + g * 4;
#pragma unroll
        for (int ni = 0; ni < 2; ++ni) {
          int p = wc * 32 + ni * 16 + r;
          ushort4 pk;
          pk.x = f2bf(acc[mi][ni][0]); pk.y = f2bf(acc[mi][ni][1]);
          pk.z = f2bf(acc[mi][ni][2]); pk.w = f2bf(acc[mi][ni][3]);
          *reinterpret_cast<ushort4*>(dst + (long)p * SEQL + s0) = pk;
        }
      }
    }
  } else {
#pragma unroll
    for (int ni = 0; ni < 2; ++ni) {
      int c = n0 + wc * 32 + ni * 16 + r;
      float bv = bias[c];
#pragma unroll
      for (int mi = 0; mi < 4; ++mi) {
        int s0 = m0 + wr * 64 + mi * 16 + g * 4;
#pragma unroll
        for (int v = 0; v < 4; ++v)
          outf[(long)(s0 + v) * FINALD + c] = acc[mi][ni][v] + bv;
      }
    }
  }
}

// ---- fused sigmoid attention: counted-vmcnt double-buffered pipeline ---
// grid 512, block 256 (4 waves x 16 q-rows). Each XCD owns 2 heads.
__global__ __launch_bounds__(256) void k_attn(
    const unsigned short* __restrict__ Qb,   // [H][S][P]
    const unsigned short* __restrict__ Kb,   // [H][S][P]
    const unsigned short* __restrict__ Vtb,  // [H][P][S]
    unsigned short* __restrict__ Ab) {       // [H][S][P] bf16
  __shared__ char lds[40960];
  int b = blockIdx.x;
  int xcd = b & 7, j = b >> 3;
  int h = (xcd << 1) | (j & 1);   // heads {2*xcd, 2*xcd+1} pinned to xcd
  int sblk = j >> 1;              // 0..31
  int lane = threadIdx.x & 63, wave = threadIdx.x >> 6;
  int r = lane & 15, g = lane >> 4;
  int q0 = sblk * 64 + wave * 16;
  const unsigned short* Qh = Qb + ((long)h * SEQL + q0) * HEADP;
  const unsigned short* Kh = Kb + (long)h * SEQL * HEADP;
  const unsigned short* Vh = Vtb + (long)h * HEADP * SEQL;

  bf16x8 qf0 = *reinterpret_cast<const bf16x8*>(Qh + (long)r * HEADP + g * 8);
  bf16x8 qf1 = *reinterpret_cast<const bf16x8*>(Qh + (long)r * HEADP + 32 + g * 8);

  f32x4 z4 = {0.f, 0.f, 0.f, 0.f};
  f32x4 oacc[4] = {z4, z4, z4, z4};
  char* slab = lds + 32768 + wave * 2048;
  int swz = (r & 7) << 4;
  const float CLN = -0.02254211001389005f;   // -log2(e)/64

  int sub = lane >> 3, chunk = lane & 7;
  auto stage = [&](int buf, int t0) {
    char* kb = lds + buf * 16384 + wave * 2048;
    char* vb = kb + 8192;
#pragma unroll
    for (int jj = 0; jj < 2; ++jj) {
      int row = wave * 16 + jj * 8 + sub;
      int sw = (chunk ^ (row & 7)) * 8;
      gload16(Kh + (long)(t0 + row) * HEADP + sw, kb + jj * 1024);
      gload16(Vh + (long)row * SEQL + t0 + sw, vb + jj * 1024);
    }
  };

  int cur = 0;
  stage(0, 0);                               // 4 loads in flight
  for (int t0 = 0; t0 < SEQL; t0 += 64) {
    __builtin_amdgcn_s_barrier();            // A: all done reading buf cur^1
    if (t0 + 64 < SEQL) {
      stage(cur ^ 1, t0 + 64);               // 4 more loads (8 outstanding)
      WAITV(4);                              // cur's loads landed
    } else {
      WAITV(0);
    }
    __builtin_amdgcn_s_barrier();            // B: everyone's cur loads landed
    __builtin_amdgcn_sched_barrier(0);

    const char* kb = lds + cur * 16384;
    const char* vb = kb + 8192;
    // S^T = K @ Q^T : lane holds S[t=tb*16+g*4+v][q=r]
    f32x4 s[4] = {z4, z4, z4, z4};
    __builtin_amdgcn_s_setprio(1);
#pragma unroll
    for (int tb = 0; tb < 4; ++tb) {
      const char* krow = kb + (tb * 16 + r) * 128;
      bf16x8 k0 = *reinterpret_cast<const bf16x8*>(krow + ((g ^ (r & 7)) * 16));
      bf16x8 k1 = *reinterpret_cast<const bf16x8*>(krow + (((4 + g) ^ (r & 7)) * 16));
      s[tb] = mfma16(k0, qf0, s[tb]);
      s[tb] = mfma16(k1, qf1, s[tb]);
    }
    __builtin_amdgcn_s_setprio(0);
    // sigmoid(S/64) -> bf16 -> per-wave slab (8B writes, swizzled)
#pragma unroll
    for (int tb = 0; tb < 4; ++tb) {
      s16x4 pk;
#pragma unroll
      for (int v = 0; v < 4; ++v) {
        float e = __builtin_amdgcn_exp2f(s[tb][v] * CLN);
        pk[v] = (short)f2bf(__builtin_amdgcn_rcpf(1.0f + e));
      }
      *reinterpret_cast<s16x4*>(slab + r * 128 + ((tb * 32 + g * 8) ^ swz)) = pk;
    }
    // PV: A-frags from slab, B-frags from V tile in LDS
    bf16x8 pa0 = *reinterpret_cast<const bf16x8*>(slab + r * 128 + ((g * 16) ^ swz));
    bf16x8 pa1 = *reinterpret_cast<const bf16x8*>(slab + r * 128 + ((64 + g * 16) ^ swz));
    __builtin_amdgcn_s_setprio(1);
#pragma unroll
    for (int nb = 0; nb < 4; ++nb) {
      const char* vrow = vb + (nb * 16 + r) * 128;
      bf16x8 v0 = *reinterpret_cast<const bf16x8*>(vrow + ((g ^ (r & 7)) * 16));
      bf16x8 v1 = *reinterpret_cast<const bf16x8*>(vrow + (((4 + g) ^ (r & 7)) * 16));
      oacc[nb] = mfma16(pa0, v0, oacc[nb]);
      oacc[nb] = mfma16(pa1, v1, oacc[nb]);
    }
    __builtin_amdgcn_s_setprio(0);
    cur ^= 1;
  }
  unsigned short* Oh = Ab + ((long)h * SEQL + q0) * HEADP;
#pragma unroll
  for (int nb = 0; nb < 4; ++nb)
#pragma unroll
    for (int v = 0; v < 4; ++v)
      Oh[(g * 4 + v) * HEADP + nb * 16 + r] = f2bf(oacc[nb][v]);
}

// ---- launch -------------------------------------------------------------
extern "C" void kernel_launch(void* const* d_in, const int* in_sizes, int n_in,
                              void* d_out, int out_size, void* d_ws, size_t ws_size,
                              hipStream_t stream) {
  const float* x  = (const float*)d_in[0];
  const float* Qw = (const float*)d_in[1];
  const float* Kw = (const float*)d_in[2];
  const float* Vw = (const float*)d_in[3];
  const float* Wf = (const float*)d_in[4];
  const float* bf = (const float*)d_in[5];
  float* out = (float*)d_out;

  unsigned short* ws  = (unsigned short*)d_ws;
  unsigned short* xb  = ws;                // [2048][1024]       bytes [0,4M)
  unsigned short* Wt  = ws + 2097152;      // [3][16][64][1024]  bytes [4M,10M)  == B^T [3072][1024]
  unsigned short* WfT = ws + 5242880;      // [1024][1024]       bytes [10M,12M)
  unsigned short* Qb  = ws + 6291456;      // [16][2048][64]     bytes [12M,16M)
  unsigned short* Kb  = ws + 8388608;      //                    bytes [16M,20M)
  unsigned short* Vtb = ws + 10485760;     // [16][64][2048]     bytes [20M,24M)
  unsigned short* Ab  = ws + 12582912;     // [16][2048][64]     bytes [24M,28M)

  k_prep<<<dim3(16, 16, 5), 256, 0, stream>>>(Qw, Kw, Vw, Wf, x, Wt, WfT, xb);
  k_gemm<0><<<dim3(16, 48), 256, 0, stream>>>(xb, Wt, DMODEL, Qb, Kb, Vtb, nullptr, nullptr);
  k_attn<<<512, 256, 0, stream>>>(Qb, Kb, Vtb, Ab);
  k_gemm<1><<<dim3(16, 16), 256, 0, stream>>>(Ab, WfT, DMODEL, nullptr, nullptr, nullptr, bf, out);
}